// Round 2
// baseline (417.398 us; speedup 1.0000x reference)
//
#include <hip/hip_runtime.h>

typedef unsigned short u16;
typedef unsigned int   u32;
typedef __attribute__((ext_vector_type(8))) short bf16x8;
typedef __attribute__((ext_vector_type(4))) float f32x4;

#define DEVFN __device__ __forceinline__

DEVFN float b2f(u16 u){ u32 t=((u32)u)<<16; float f; __builtin_memcpy(&f,&t,4); return f; }
DEVFN u16 f2b(float f){ u32 t; __builtin_memcpy(&t,&f,4); t += 0x7fffu + ((t>>16)&1u); return (u16)(t>>16); }
DEVFN float bl(u32 u){ u32 t=u<<16; float f; __builtin_memcpy(&f,&t,4); return f; }
DEVFN float bh(u32 u){ u32 t=u&0xffff0000u; float f; __builtin_memcpy(&f,&t,4); return f; }

// ---------- transpose fp32 -> bf16: dst[C][R] = bf16(src[R][C])
__global__ __launch_bounds__(256) void tr_k(const float* __restrict__ src, u16* __restrict__ dst, int R, int C){
  __shared__ u16 tile[32][33];
  int bx = blockIdx.x*32, by = blockIdx.y*32;
  int tx = threadIdx.x&31, ty = threadIdx.x>>5;
  #pragma unroll
  for(int yy=ty; yy<32; yy+=8) tile[yy][tx] = f2b(src[(size_t)(by+yy)*C + bx+tx]);
  __syncthreads();
  #pragma unroll
  for(int yy=ty; yy<32; yy+=8) dst[(size_t)(bx+yy)*R + by+tx] = tile[tx][yy];
}

// ---------- LUT: pr -> (j<<16)|i for upper-triangle pairs j<=i, N=89, padded to 4096
__global__ void lut_k(u32* __restrict__ lut){
  int t = threadIdx.x;
  if(t < 89){
    int base = t*89 - (t*(t-1))/2;
    for(int i=t;i<89;i++) lut[base + (i-t)] = ((u32)t<<16) | (u32)i;
  } else {
    int p = 4005 + (t-89);
    if(p < 4096) lut[p] = 0;
  }
}

// ---------- pgen: p[row,:] = bf16(x[b,j,:]*x[b,i,:]), rows = 4096 per batch, x fp32
__global__ __launch_bounds__(256) void pgen_k(const float* __restrict__ x, const u32* __restrict__ lut,
                                              u16* __restrict__ p, long pz, int bbase){
  int z = blockIdx.y, b = bbase + z, row = blockIdx.x;
  u32 ji = lut[row]; int j = (int)(ji>>16), i = (int)(ji & 0xffff);
  const float* xb = x + (size_t)b*91136;  // 89*1024
  int c = threadIdx.x*4;
  float4 a  = *(const float4*)(xb + (size_t)j*1024 + c);
  float4 bb = *(const float4*)(xb + (size_t)i*1024 + c);
  ushort4 o;
  o.x = f2b(a.x*bb.x);
  o.y = f2b(a.y*bb.y);
  o.z = f2b(a.z*bb.z);
  o.w = f2b(a.w*bb.w);
  *(ushort4*)(p + (size_t)z*pz + (size_t)row*1024 + c) = o;
}

// ---------- staging: 128 rows x 64 k (bf16) via global_load_lds, XOR-swizzled k-blocks
// source rows have stride 1024 bf16 elements (true for all staged matrices here)
DEVFN void stage_gl(const u16* __restrict__ g0, u16* lds0, int tid){
  int w = tid>>6, lane = tid&63;
  #pragma unroll
  for(int i=0;i<4;i++){
    int p  = (w*4+i)*64 + lane;         // slot index 0..1023 (16B slots)
    int r  = p>>3;                       // row 0..127
    int kb = (p&7) ^ (r&7);              // logical k-block for this physical slot
    const u16* g = g0 + ((size_t)r<<10) + (kb<<3);
    u16* l = lds0 + (size_t)(w*4+i)*512; // wave-uniform base; lane*16B appended by HW
    __builtin_amdgcn_global_load_lds((const __attribute__((address_space(1))) u32*)g,
                                     (__attribute__((address_space(3))) u32*)l, 16, 0, 0);
  }
}

// ---------- GEMM: out = epi(A @ B^T_rows + bias), tiles 128x128, BK=64, 4 waves, 4x4 frags
// AMODE: 0 = single source, 1 = dual (two K=1024 contractions summed: A0@B0 + A1@B1)
// EPI:   0 = relu+bias -> bf16 ws ; 1 = final ((x + acc + bias0 + bias1)/3) -> fp32 d_out
template<int AMODE, int EPI>
__global__ __launch_bounds__(256,2) void gemm_k(
    const u16* __restrict__ A0, const u16* __restrict__ B0,
    const u16* __restrict__ A1, const u16* __restrict__ B1,
    const float* __restrict__ bias0, const float* __restrict__ bias1,
    const float* __restrict__ xres, void* __restrict__ out,
    long a0z, long oz, int ldo, int mvalid, int kiters)
{
  __shared__ __align__(16) u16 As[128*64];
  __shared__ __align__(16) u16 Bs[128*64];
  int tid = threadIdx.x;
  int m0 = blockIdx.y*128, n0 = blockIdx.x*128, z = blockIdx.z;
  const u16* Abase0 = A0 + (size_t)z*a0z + (size_t)m0*1024;

  f32x4 acc[4][4];
  #pragma unroll
  for(int a=0;a<4;a++)
    #pragma unroll
    for(int b=0;b<4;b++) acc[a][b] = (f32x4){0.f,0.f,0.f,0.f};

  int w = tid>>6, lane = tid&63, quad = lane>>4, l15 = lane&15;
  int wr = (w>>1)*64, wc = (w&1)*64;

  for(int kk=0; kk<kiters; kk++){
    int k0 = (kk & 15) << 6;
    const u16* Ab = Abase0 + k0;
    const u16* Bb = B0 + (size_t)n0*1024 + k0;
    if(AMODE==1 && kk>=16){
      Ab = A1 + (size_t)m0*1024 + k0;
      Bb = B1 + (size_t)n0*1024 + k0;
    }
    __syncthreads();
    stage_gl(Ab, As, tid);
    stage_gl(Bb, Bs, tid);
    __syncthreads();
    #pragma unroll
    for(int kq=0; kq<2; kq++){
      int kbl = kq*4 + quad;
      bf16x8 af[4], bfv[4];
      #pragma unroll
      for(int t=0;t<4;t++){
        int rr = wr + t*16 + l15;
        af[t] = *(const bf16x8*)(As + rr*64 + ((kbl ^ (rr&7))<<3));
      }
      #pragma unroll
      for(int t=0;t<4;t++){
        int cc = wc + t*16 + l15;
        bfv[t] = *(const bf16x8*)(Bs + cc*64 + ((kbl ^ (cc&7))<<3));
      }
      #pragma unroll
      for(int rt=0;rt<4;rt++)
        #pragma unroll
        for(int ct=0;ct<4;ct++)
          acc[rt][ct] = __builtin_amdgcn_mfma_f32_16x16x32_bf16(af[rt], bfv[ct], acc[rt][ct], 0,0,0);
    }
  }

  #pragma unroll
  for(int ct=0;ct<4;ct++){
    int colg = n0 + wc + ct*16 + l15;
    float bc = bias0[colg];
    if(EPI==1) bc += bias1[colg];
    #pragma unroll
    for(int rt=0;rt<4;rt++){
      #pragma unroll
      for(int r=0;r<4;r++){
        int rowg = m0 + wr + rt*16 + quad*4 + r;
        float v = acc[rt][ct][r] + bc;
        if(EPI==0){
          v = fmaxf(v, 0.f);
          ((u16*)out)[(size_t)z*oz + (size_t)rowg*ldo + colg] = f2b(v);
        } else {
          if(rowg < mvalid){
            v = (v + xres[(size_t)rowg*1024 + colg]) * (1.f/3.f);
            ((float*)out)[(size_t)rowg*ldo + colg] = v;
          }
        }
      }
    }
  }
}

// ---------- layer3 + sigmoid + symmetric scatter of s
__global__ __launch_bounds__(256) void k3_k(const u16* __restrict__ h2, long h2z,
    const float* __restrict__ Wa3, const float* __restrict__ ba3,
    const u32* __restrict__ lut, float* __restrict__ s, int bbase)
{
  int z = blockIdx.y, b = bbase + z;
  int row = blockIdx.x*4 + (threadIdx.x>>6);
  if(row >= 4005) return;
  int lane = threadIdx.x & 63;
  const u16* hr = h2 + (size_t)z*h2z + (size_t)row*512 + lane*8;
  uint4 hv = *(const uint4*)hr;
  float4 w0 = *(const float4*)(Wa3 + lane*8);
  float4 w1 = *(const float4*)(Wa3 + lane*8 + 4);
  float sum = bl(hv.x)*w0.x + bh(hv.x)*w0.y
            + bl(hv.y)*w0.z + bh(hv.y)*w0.w
            + bl(hv.z)*w1.x + bh(hv.z)*w1.y
            + bl(hv.w)*w1.z + bh(hv.w)*w1.w;
  #pragma unroll
  for(int m=32;m>0;m>>=1) sum += __shfl_xor(sum, m, 64);
  if(lane==0){
    u32 ji = lut[row]; int j = (int)(ji>>16), i = (int)(ji & 0xffff);
    float val = 1.f/(1.f + expf(-(sum + ba3[0])));
    s[(size_t)b*7921 + j*89 + i] = val;
    s[(size_t)b*7921 + i*89 + j] = val;
  }
}

// ---------- AddConv / ModulatorConv aggregation -> a_t, m_t (bf16); x/adj fp32
__global__ __launch_bounds__(256) void k4_k(const float* __restrict__ x,
    const float* __restrict__ adjA, const float* __restrict__ adjM,
    const float* __restrict__ s, u16* __restrict__ a_t, u16* __restrict__ m_t)
{
  int b = blockIdx.y, i = blockIdx.x, t = threadIdx.x;
  __shared__ float ca[89], cm[89];
  if(t < 89){
    ca[t] = s[(size_t)b*7921 + t*89 + i] * adjA[t*89 + i];
    cm[t] = adjM[t*89 + i];
  }
  __syncthreads();
  const float* xb = x + (size_t)b*91136;
  int c0 = t*4;
  float aa0=0,aa1=0,aa2=0,aa3=0, am0=0,am1=0,am2=0,am3=0;
  for(int j=0;j<89;j++){
    float4 xv = *(const float4*)(xb + (size_t)j*1024 + c0);
    float fa=ca[j], fm=cm[j];
    aa0+=fa*xv.x; aa1+=fa*xv.y; aa2+=fa*xv.z; aa3+=fa*xv.w;
    am0+=fm*xv.x; am1+=fm*xv.y; am2+=fm*xv.z; am3+=fm*xv.w;
  }
  float4 xi = *(const float4*)(xb + (size_t)i*1024 + c0);
  size_t ro = ((size_t)(b*89 + i))*1024 + c0;
  ushort4 oa; oa.x=f2b(aa0); oa.y=f2b(aa1); oa.z=f2b(aa2); oa.w=f2b(aa3);
  ushort4 om;
  om.x=f2b(xi.x*am0); om.y=f2b(xi.y*am1);
  om.z=f2b(xi.z*am2); om.w=f2b(xi.w*am3);
  *(ushort4*)(a_t + ro) = oa;
  *(ushort4*)(m_t + ro) = om;
}

extern "C" void kernel_launch(void* const* d_in, const int* in_sizes, int n_in,
                              void* d_out, int out_size, void* d_ws, size_t ws_size,
                              hipStream_t stream)
{
  const float* X     = (const float*)d_in[0];
  const float* adjA  = (const float*)d_in[1];
  const float* adjM  = (const float*)d_in[2];
  const float* Wa1   = (const float*)d_in[3];
  const float* ba1   = (const float*)d_in[4];
  const float* Wa2   = (const float*)d_in[5];
  const float* ba2   = (const float*)d_in[6];
  const float* Wa3   = (const float*)d_in[7];
  const float* ba3   = (const float*)d_in[8];
  const float* Wadd1 = (const float*)d_in[9];
  const float* badd1 = (const float*)d_in[10];
  const float* Wadd2 = (const float*)d_in[11];
  const float* badd2 = (const float*)d_in[12];
  const float* Wmod1 = (const float*)d_in[13];
  const float* bmod1 = (const float*)d_in[14];
  const float* Wmod2 = (const float*)d_in[15];
  const float* bmod2 = (const float*)d_in[16];

  char* w = (char*)d_ws;
  u16* WaT1   = (u16*)w; w += (size_t)1024*1024*2;
  u16* WaT2   = (u16*)w; w += (size_t)512*1024*2;
  u16* WaddT1 = (u16*)w; w += (size_t)1024*1024*2;
  u16* WaddT2 = (u16*)w; w += (size_t)1024*1024*2;
  u16* WmodT1 = (u16*)w; w += (size_t)1024*1024*2;
  u16* WmodT2 = (u16*)w; w += (size_t)1024*1024*2;
  u32* lut    = (u32*)w; w += 4096*4;
  float* s    = (float*)w; w += 253504;           // 8*7921*4, 64B-rounded
  u16* a_t    = (u16*)w; w += (size_t)768*1024*2;
  u16* m_t    = (u16*)w; w += (size_t)768*1024*2;
  u16* ha     = (u16*)w; w += (size_t)768*1024*2;
  u16* hm     = (u16*)w; w += (size_t)768*1024*2;
  size_t fixed = (size_t)(w - (char*)d_ws);
  size_t per_p = (size_t)4096*1024*2, per_h1 = (size_t)4096*1024*2, per_h2 = (size_t)4096*512*2;
  bool flat = ws_size >= fixed + 8*(per_p + per_h1 + per_h2);
  int nb = flat ? 8 : 1;
  u16* pbuf = (u16*)w; w += per_p  * nb;
  u16* h1   = (u16*)w; w += per_h1 * nb;
  u16* h2   = (u16*)w;

  tr_k<<<dim3(32,32),256,0,stream>>>(Wa1,   WaT1,   1024, 1024);
  tr_k<<<dim3(16,32),256,0,stream>>>(Wa2,   WaT2,   1024, 512);
  tr_k<<<dim3(32,32),256,0,stream>>>(Wadd1, WaddT1, 1024, 1024);
  tr_k<<<dim3(32,32),256,0,stream>>>(Wadd2, WaddT2, 1024, 1024);
  tr_k<<<dim3(32,32),256,0,stream>>>(Wmod1, WmodT1, 1024, 1024);
  tr_k<<<dim3(32,32),256,0,stream>>>(Wmod2, WmodT2, 1024, 1024);
  lut_k<<<1,256,0,stream>>>(lut);

  long pz = 4096*1024, h1z = 4096*1024, h2z = 4096*512;
  for(int bb=0; bb<8; bb+=nb){
    pgen_k<<<dim3(4096,nb),256,0,stream>>>(X, lut, pbuf, pz, bb);
    gemm_k<0,0><<<dim3(8,32,nb),256,0,stream>>>(pbuf, WaT1, nullptr,nullptr, ba1,nullptr,nullptr,
                                                h1, pz, h1z, 1024, 4096, 16);
    gemm_k<0,0><<<dim3(4,32,nb),256,0,stream>>>(h1, WaT2, nullptr,nullptr, ba2,nullptr,nullptr,
                                                h2, h1z, h2z, 512, 4096, 16);
    k3_k<<<dim3(1002,nb),256,0,stream>>>(h2, h2z, Wa3, ba3, lut, s, bb);
  }
  k4_k<<<dim3(89,8),256,0,stream>>>(X, adjA, adjM, s, a_t, m_t);
  gemm_k<0,0><<<dim3(8,6,1),256,0,stream>>>(a_t, WaddT1, nullptr,nullptr, badd1,nullptr,nullptr,
                                            ha, 0,0, 1024, 768, 16);
  gemm_k<0,0><<<dim3(8,6,1),256,0,stream>>>(m_t, WmodT1, nullptr,nullptr, bmod1,nullptr,nullptr,
                                            hm, 0,0, 1024, 768, 16);
  gemm_k<1,1><<<dim3(8,6,1),256,0,stream>>>(ha, WaddT2, hm, WmodT2, badd2, bmod2, X,
                                            (float*)d_out, 0,0, 1024, 712, 32);
}

// Round 3
// 362.938 us; speedup vs baseline: 1.1501x; 1.1501x over previous
//
#include <hip/hip_runtime.h>

typedef unsigned short u16;
typedef unsigned int   u32;
typedef __attribute__((ext_vector_type(8))) short bf16x8;
typedef __attribute__((ext_vector_type(4))) float f32x4;

#define DEVFN __device__ __forceinline__

DEVFN float b2f(u16 u){ u32 t=((u32)u)<<16; float f; __builtin_memcpy(&f,&t,4); return f; }
DEVFN u16 f2b(float f){ u32 t; __builtin_memcpy(&t,&f,4); t += 0x7fffu + ((t>>16)&1u); return (u16)(t>>16); }
DEVFN float bl(u32 u){ u32 t=u<<16; float f; __builtin_memcpy(&f,&t,4); return f; }
DEVFN float bh(u32 u){ u32 t=u&0xffff0000u; float f; __builtin_memcpy(&f,&t,4); return f; }

// row -> (j,i) for upper-triangle pairs j<=i, N=89; base(j) = j*(179-j)/2
DEVFN void row2ji(int row, int* jj, int* ii){
  int j = (int)((179.0f - sqrtf(179.0f*179.0f - 8.0f*(float)row)) * 0.5f);
  if(j < 0) j = 0; if(j > 88) j = 88;
  while(j < 88 && (j+1)*(179-(j+1))/2 <= row) j++;
  while(j > 0 && j*(179-j)/2 > row) j--;
  *jj = j;
  *ii = j + (row - j*(179-j)/2);
}

// ---------- fused weight transposes fp32 -> bf16: dst[C][1024] = bf16(src[1024][C])
struct TrArgs { const float* src; u16* dst; int C; };
struct TrPack { TrArgs a[6]; };
__global__ __launch_bounds__(256) void trw_k(TrPack pk){
  TrArgs t = pk.a[blockIdx.z];
  int bx = blockIdx.x*32, by = blockIdx.y*32;
  if(bx >= t.C) return;
  __shared__ u16 tile[32][33];
  int tx = threadIdx.x&31, ty = threadIdx.x>>5;
  #pragma unroll
  for(int yy=ty; yy<32; yy+=8) tile[yy][tx] = f2b(t.src[(size_t)(by+yy)*t.C + bx+tx]);
  __syncthreads();
  #pragma unroll
  for(int yy=ty; yy<32; yy+=8) t.dst[(size_t)(bx+yy)*1024 + by+tx] = tile[tx][yy];
}

// ---------- pgen: p[row,:] = bf16(x[b,j,:]*x[b,i,:]), rows = 4096 per batch, x fp32
__global__ __launch_bounds__(256) void pgen_k(const float* __restrict__ x,
                                              u16* __restrict__ p, long pz, int bbase){
  int z = blockIdx.y, b = bbase + z, row = blockIdx.x;
  int j, i; row2ji(row < 4005 ? row : 0, &j, &i);
  const float* xb = x + (size_t)b*91136;  // 89*1024
  int c = threadIdx.x*4;
  float4 a  = *(const float4*)(xb + (size_t)j*1024 + c);
  float4 bb = *(const float4*)(xb + (size_t)i*1024 + c);
  ushort4 o;
  o.x = f2b(a.x*bb.x);
  o.y = f2b(a.y*bb.y);
  o.z = f2b(a.z*bb.z);
  o.w = f2b(a.w*bb.w);
  *(ushort4*)(p + (size_t)z*pz + (size_t)row*1024 + c) = o;
}

// ---------- staging: 128 rows x 64 k (bf16) via global_load_lds, XOR-swizzled k-blocks
// source rows have stride 1024 bf16 elements (true for all staged matrices here)
DEVFN void stage_gl(const u16* __restrict__ g0, u16* lds0, int tid){
  int w = tid>>6, lane = tid&63;
  #pragma unroll
  for(int i=0;i<4;i++){
    int p  = (w*4+i)*64 + lane;         // slot index 0..1023 (16B slots)
    int r  = p>>3;                       // row 0..127
    int kb = (p&7) ^ (r&7);              // logical k-block for this physical slot
    const u16* g = g0 + ((size_t)r<<10) + (kb<<3);
    u16* l = lds0 + (size_t)(w*4+i)*512; // wave-uniform base; lane*16B appended by HW
    __builtin_amdgcn_global_load_lds((const __attribute__((address_space(1))) u32*)g,
                                     (__attribute__((address_space(3))) u32*)l, 16, 0, 0);
  }
}

// ---------- GEMM: out = epi(A @ B^T_rows + bias), tiles 128x128, BK=64, 4 waves, 4x4 frags
// Grid is (1, nblk*mblk, nb); blockIdx.y = n*mblk + m (m fastest) so the blocks sharing
// one A-tile keep the same (linear%8) AND the same contiguous chunk -> same XCD -> A-tile
// is fetched from HBM once and L2-served afterwards.
// AMODE: 0 = single source, 1 = dual (two K=1024 contractions summed: A0@B0 + A1@B1)
// EPI:   0 = relu+bias -> bf16 ws ; 1 = final ((x + acc + bias0 + bias1)/3) -> fp32 d_out
template<int AMODE, int EPI>
__global__ __launch_bounds__(256,2) void gemm_k(
    const u16* __restrict__ A0, const u16* __restrict__ B0,
    const u16* __restrict__ A1, const u16* __restrict__ B1,
    const float* __restrict__ bias0, const float* __restrict__ bias1,
    const float* __restrict__ xres, void* __restrict__ out,
    long a0z, long oz, int ldo, int mvalid, int kiters,
    int mmask, int mshift, int mlimit)
{
  int by = blockIdx.y;
  int m0 = (by & mmask)*128, n0 = (by >> mshift)*128, z = blockIdx.z;
  if(m0 >= mlimit) return;   // block-uniform: safe before barriers

  __shared__ __align__(16) u16 As[128*64];
  __shared__ __align__(16) u16 Bs[128*64];
  int tid = threadIdx.x;
  const u16* Abase0 = A0 + (size_t)z*a0z + (size_t)m0*1024;

  f32x4 acc[4][4];
  #pragma unroll
  for(int a=0;a<4;a++)
    #pragma unroll
    for(int b=0;b<4;b++) acc[a][b] = (f32x4){0.f,0.f,0.f,0.f};

  int w = tid>>6, lane = tid&63, quad = lane>>4, l15 = lane&15;
  int wr = (w>>1)*64, wc = (w&1)*64;

  for(int kk=0; kk<kiters; kk++){
    int k0 = (kk & 15) << 6;
    const u16* Ab = Abase0 + k0;
    const u16* Bb = B0 + (size_t)n0*1024 + k0;
    if(AMODE==1 && kk>=16){
      Ab = A1 + (size_t)m0*1024 + k0;
      Bb = B1 + (size_t)n0*1024 + k0;
    }
    __syncthreads();
    stage_gl(Ab, As, tid);
    stage_gl(Bb, Bs, tid);
    __syncthreads();
    #pragma unroll
    for(int kq=0; kq<2; kq++){
      int kbl = kq*4 + quad;
      bf16x8 af[4], bfv[4];
      #pragma unroll
      for(int t=0;t<4;t++){
        int rr = wr + t*16 + l15;
        af[t] = *(const bf16x8*)(As + rr*64 + ((kbl ^ (rr&7))<<3));
      }
      #pragma unroll
      for(int t=0;t<4;t++){
        int cc = wc + t*16 + l15;
        bfv[t] = *(const bf16x8*)(Bs + cc*64 + ((kbl ^ (cc&7))<<3));
      }
      #pragma unroll
      for(int rt=0;rt<4;rt++)
        #pragma unroll
        for(int ct=0;ct<4;ct++)
          acc[rt][ct] = __builtin_amdgcn_mfma_f32_16x16x32_bf16(af[rt], bfv[ct], acc[rt][ct], 0,0,0);
    }
  }

  #pragma unroll
  for(int ct=0;ct<4;ct++){
    int colg = n0 + wc + ct*16 + l15;
    float bc = bias0[colg];
    if(EPI==1) bc += bias1[colg];
    #pragma unroll
    for(int rt=0;rt<4;rt++){
      #pragma unroll
      for(int r=0;r<4;r++){
        int rowg = m0 + wr + rt*16 + quad*4 + r;
        float v = acc[rt][ct][r] + bc;
        if(EPI==0){
          v = fmaxf(v, 0.f);
          ((u16*)out)[(size_t)z*oz + (size_t)rowg*ldo + colg] = f2b(v);
        } else {
          if(rowg < mvalid){
            v = (v + xres[(size_t)rowg*1024 + colg]) * (1.f/3.f);
            ((float*)out)[(size_t)rowg*ldo + colg] = v;
          }
        }
      }
    }
  }
}

// ---------- layer3 + sigmoid + symmetric scatter of s
__global__ __launch_bounds__(256) void k3_k(const u16* __restrict__ h2, long h2z,
    const float* __restrict__ Wa3, const float* __restrict__ ba3,
    float* __restrict__ s, int bbase)
{
  int z = blockIdx.y, b = bbase + z;
  int row = blockIdx.x*4 + (threadIdx.x>>6);
  if(row >= 4005) return;
  int lane = threadIdx.x & 63;
  const u16* hr = h2 + (size_t)z*h2z + (size_t)row*512 + lane*8;
  uint4 hv = *(const uint4*)hr;
  float4 w0 = *(const float4*)(Wa3 + lane*8);
  float4 w1 = *(const float4*)(Wa3 + lane*8 + 4);
  float sum = bl(hv.x)*w0.x + bh(hv.x)*w0.y
            + bl(hv.y)*w0.z + bh(hv.y)*w0.w
            + bl(hv.z)*w1.x + bh(hv.z)*w1.y
            + bl(hv.w)*w1.z + bh(hv.w)*w1.w;
  #pragma unroll
  for(int m=32;m>0;m>>=1) sum += __shfl_xor(sum, m, 64);
  if(lane==0){
    int j, i; row2ji(row, &j, &i);
    float val = 1.f/(1.f + expf(-(sum + ba3[0])));
    s[(size_t)b*7921 + j*89 + i] = val;
    s[(size_t)b*7921 + i*89 + j] = val;
  }
}

// ---------- AddConv / ModulatorConv aggregation -> a_t, m_t (bf16); x/adj fp32
__global__ __launch_bounds__(256) void k4_k(const float* __restrict__ x,
    const float* __restrict__ adjA, const float* __restrict__ adjM,
    const float* __restrict__ s, u16* __restrict__ a_t, u16* __restrict__ m_t)
{
  int b = blockIdx.y, i = blockIdx.x, t = threadIdx.x;
  __shared__ float ca[89], cm[89];
  if(t < 89){
    ca[t] = s[(size_t)b*7921 + t*89 + i] * adjA[t*89 + i];
    cm[t] = adjM[t*89 + i];
  }
  __syncthreads();
  const float* xb = x + (size_t)b*91136;
  int c0 = t*4;
  float aa0=0,aa1=0,aa2=0,aa3=0, am0=0,am1=0,am2=0,am3=0;
  for(int j=0;j<89;j++){
    float4 xv = *(const float4*)(xb + (size_t)j*1024 + c0);
    float fa=ca[j], fm=cm[j];
    aa0+=fa*xv.x; aa1+=fa*xv.y; aa2+=fa*xv.z; aa3+=fa*xv.w;
    am0+=fm*xv.x; am1+=fm*xv.y; am2+=fm*xv.z; am3+=fm*xv.w;
  }
  float4 xi = *(const float4*)(xb + (size_t)i*1024 + c0);
  size_t ro = ((size_t)(b*89 + i))*1024 + c0;
  ushort4 oa; oa.x=f2b(aa0); oa.y=f2b(aa1); oa.z=f2b(aa2); oa.w=f2b(aa3);
  ushort4 om;
  om.x=f2b(xi.x*am0); om.y=f2b(xi.y*am1);
  om.z=f2b(xi.z*am2); om.w=f2b(xi.w*am3);
  *(ushort4*)(a_t + ro) = oa;
  *(ushort4*)(m_t + ro) = om;
}

extern "C" void kernel_launch(void* const* d_in, const int* in_sizes, int n_in,
                              void* d_out, int out_size, void* d_ws, size_t ws_size,
                              hipStream_t stream)
{
  const float* X     = (const float*)d_in[0];
  const float* adjA  = (const float*)d_in[1];
  const float* adjM  = (const float*)d_in[2];
  const float* Wa1   = (const float*)d_in[3];
  const float* ba1   = (const float*)d_in[4];
  const float* Wa2   = (const float*)d_in[5];
  const float* ba2   = (const float*)d_in[6];
  const float* Wa3   = (const float*)d_in[7];
  const float* ba3   = (const float*)d_in[8];
  const float* Wadd1 = (const float*)d_in[9];
  const float* badd1 = (const float*)d_in[10];
  const float* Wadd2 = (const float*)d_in[11];
  const float* badd2 = (const float*)d_in[12];
  const float* Wmod1 = (const float*)d_in[13];
  const float* bmod1 = (const float*)d_in[14];
  const float* Wmod2 = (const float*)d_in[15];
  const float* bmod2 = (const float*)d_in[16];

  char* w = (char*)d_ws;
  u16* WaT1   = (u16*)w; w += (size_t)1024*1024*2;
  u16* WaT2   = (u16*)w; w += (size_t)512*1024*2;
  u16* WaddT1 = (u16*)w; w += (size_t)1024*1024*2;
  u16* WaddT2 = (u16*)w; w += (size_t)1024*1024*2;
  u16* WmodT1 = (u16*)w; w += (size_t)1024*1024*2;
  u16* WmodT2 = (u16*)w; w += (size_t)1024*1024*2;
  float* s    = (float*)w; w += 253504;           // 8*7921*4, 64B-rounded
  u16* a_t    = (u16*)w; w += (size_t)768*1024*2;
  u16* m_t    = (u16*)w; w += (size_t)768*1024*2;
  u16* ha     = (u16*)w; w += (size_t)768*1024*2;
  u16* hm     = (u16*)w; w += (size_t)768*1024*2;
  size_t fixed = (size_t)(w - (char*)d_ws);
  size_t per_p = (size_t)4096*1024*2, per_h1 = (size_t)4096*1024*2, per_h2 = (size_t)4096*512*2;
  bool flat = ws_size >= fixed + 8*(per_p + per_h1 + per_h2);
  int nb = flat ? 8 : 1;
  u16* pbuf = (u16*)w; w += per_p  * nb;
  u16* h1   = (u16*)w; w += per_h1 * nb;
  u16* h2   = (u16*)w;

  TrPack tp;
  tp.a[0].src = Wa1;   tp.a[0].dst = WaT1;   tp.a[0].C = 1024;
  tp.a[1].src = Wa2;   tp.a[1].dst = WaT2;   tp.a[1].C = 512;
  tp.a[2].src = Wadd1; tp.a[2].dst = WaddT1; tp.a[2].C = 1024;
  tp.a[3].src = Wadd2; tp.a[3].dst = WaddT2; tp.a[3].C = 1024;
  tp.a[4].src = Wmod1; tp.a[4].dst = WmodT1; tp.a[4].C = 1024;
  tp.a[5].src = Wmod2; tp.a[5].dst = WmodT2; tp.a[5].C = 1024;
  trw_k<<<dim3(32,32,6),256,0,stream>>>(tp);

  long pz = 4096*1024, h1z = 4096*1024, h2z = 4096*512;
  for(int bb=0; bb<8; bb+=nb){
    pgen_k<<<dim3(4096,nb),256,0,stream>>>(X, pbuf, pz, bb);
    // layer1: M=4096 (32 mblk), N=1024 (8 nblk): y = n*32 + m
    gemm_k<0,0><<<dim3(1,256,nb),256,0,stream>>>(pbuf, WaT1, nullptr,nullptr, ba1,nullptr,nullptr,
                                                 h1, pz, h1z, 1024, 4096, 16, 31, 5, 4096);
    // layer2: M=4096 (32 mblk), N=512 (4 nblk)
    gemm_k<0,0><<<dim3(1,128,nb),256,0,stream>>>(h1, WaT2, nullptr,nullptr, ba2,nullptr,nullptr,
                                                 h2, h1z, h2z, 512, 4096, 16, 31, 5, 4096);
    k3_k<<<dim3(1002,nb),256,0,stream>>>(h2, h2z, Wa3, ba3, s, bb);
  }
  k4_k<<<dim3(89,8),256,0,stream>>>(X, adjA, adjM, s, a_t, m_t);
  // tail GEMMs: M=768 (6 mblk, padded to 8), N=1024 (8 nblk)
  gemm_k<0,0><<<dim3(1,64,1),256,0,stream>>>(a_t, WaddT1, nullptr,nullptr, badd1,nullptr,nullptr,
                                             ha, 0,0, 1024, 768, 16, 7, 3, 768);
  gemm_k<0,0><<<dim3(1,64,1),256,0,stream>>>(m_t, WmodT1, nullptr,nullptr, bmod1,nullptr,nullptr,
                                             hm, 0,0, 1024, 768, 16, 7, 3, 768);
  gemm_k<1,1><<<dim3(1,64,1),256,0,stream>>>(ha, WaddT2, hm, WmodT2, badd2, bmod2, X,
                                             (float*)d_out, 0,0, 1024, 712, 32, 7, 3, 768);
}

// Round 4
// 317.974 us; speedup vs baseline: 1.3127x; 1.1414x over previous
//
#include <hip/hip_runtime.h>

typedef unsigned short u16;
typedef unsigned int   u32;
typedef __attribute__((ext_vector_type(8))) short bf16x8;
typedef __attribute__((ext_vector_type(4))) float f32x4;

#define DEVFN __device__ __forceinline__

DEVFN float b2f(u16 u){ u32 t=((u32)u)<<16; float f; __builtin_memcpy(&f,&t,4); return f; }
DEVFN u16 f2b(float f){ u32 t; __builtin_memcpy(&t,&f,4); t += 0x7fffu + ((t>>16)&1u); return (u16)(t>>16); }

// row -> (j,i) for upper-triangle pairs j<=i, N=89; base(j) = j*(179-j)/2
DEVFN void row2ji(int row, int* jj, int* ii){
  int j = (int)((179.0f - sqrtf(179.0f*179.0f - 8.0f*(float)row)) * 0.5f);
  if(j < 0) j = 0; if(j > 88) j = 88;
  while(j < 88 && (j+1)*(179-(j+1))/2 <= row) j++;
  while(j > 0 && j*(179-j)/2 > row) j--;
  *jj = j;
  *ii = j + (row - j*(179-j)/2);
}

struct TrArgs { const float* src; u16* dst; int C; };
struct TrPack { TrArgs a[6]; };

// pgen body: p[row,:] = bf16(x[b,j,:]*x[b,i,:])
DEVFN void pgen_body(const float* __restrict__ x, u16* __restrict__ p, long pz,
                     int z, int b, int row, int tid){
  int j, i; row2ji(row < 4005 ? row : 0, &j, &i);
  const float* xb = x + (size_t)b*91136;  // 89*1024
  int c = tid*4;
  float4 a  = *(const float4*)(xb + (size_t)j*1024 + c);
  float4 bb = *(const float4*)(xb + (size_t)i*1024 + c);
  ushort4 o;
  o.x = f2b(a.x*bb.x);
  o.y = f2b(a.y*bb.y);
  o.z = f2b(a.z*bb.z);
  o.w = f2b(a.w*bb.w);
  *(ushort4*)(p + (size_t)z*pz + (size_t)row*1024 + c) = o;
}

// ---------- fused prep: [0,6144) weight transposes, [6144,6176) logit zero,
//                        [6176,6176+4096*nb) pgen for batches 0..nb-1
__global__ __launch_bounds__(256) void prep_k(TrPack pk, float* __restrict__ logit,
                                              const float* __restrict__ x,
                                              u16* __restrict__ pbuf, long pz){
  __shared__ u16 tile[32][33];
  int id = blockIdx.x, tid = threadIdx.x;
  if(id < 6144){
    TrArgs t = pk.a[id>>10];
    int q = id & 1023;
    int bx = (q&31)*32, by = (q>>5)*32;
    if(bx >= t.C) return;
    int tx = tid&31, ty = tid>>5;
    #pragma unroll
    for(int yy=ty; yy<32; yy+=8) tile[yy][tx] = f2b(t.src[(size_t)(by+yy)*t.C + bx+tx]);
    __syncthreads();
    #pragma unroll
    for(int yy=ty; yy<32; yy+=8) t.dst[(size_t)(bx+yy)*1024 + by+tx] = tile[tx][yy];
  } else if(id < 6176){
    int idx = (id-6144)*1024 + tid*4;
    *(float4*)(logit + idx) = (float4){0.f,0.f,0.f,0.f};
  } else {
    int pid = id - 6176;
    int z = pid >> 12, row = pid & 4095;
    pgen_body(x, pbuf, pz, z, z, row, tid);   // bbase = 0 for prep
  }
}

// standalone pgen for per-batch fallback iterations
__global__ __launch_bounds__(256) void pgen_k(const float* __restrict__ x,
                                              u16* __restrict__ p, long pz, int bbase){
  pgen_body(x, p, pz, blockIdx.y, bbase + blockIdx.y, blockIdx.x, threadIdx.x);
}

// ---------- staging: 128 rows x 64 k (bf16) via global_load_lds, XOR-swizzled k-blocks
DEVFN void stage_gl(const u16* __restrict__ g0, u16* lds0, int tid){
  int w = tid>>6, lane = tid&63;
  #pragma unroll
  for(int i=0;i<4;i++){
    int p  = (w*4+i)*64 + lane;         // slot index 0..1023 (16B slots)
    int r  = p>>3;                       // row 0..127
    int kb = (p&7) ^ (r&7);              // logical k-block for this physical slot
    const u16* g = g0 + ((size_t)r<<10) + (kb<<3);
    u16* l = lds0 + (size_t)(w*4+i)*512;
    __builtin_amdgcn_global_load_lds((const __attribute__((address_space(1))) u32*)g,
                                     (__attribute__((address_space(3))) u32*)l, 16, 0, 0);
  }
}

// ---------- GEMM: tiles 128x128, BK=64, 4 waves, 4x4 frags; blockIdx.y = n*mblk + m
// AMODE: 0 = single source; 1 = dual-K (A0@B0 for kk<16, A1@B1 for kk>=16); 2 = z-select (z? A1,B1,bias1 : A0,B0,bias0)
// EPI:   0 = relu+bias -> bf16 out (+z*oz) ; 1 = final ((x + acc + bias0 + bias1)/3) -> fp32, row-guarded
//        2 = logit: relu+bias tile dotted with aux(=Wa3) chunk, lane-reduced, atomicAdd into ((float*)out)[(aux2+z)*4096 + row]
template<int AMODE, int EPI>
__global__ __launch_bounds__(256,2) void gemm_k(
    const u16* __restrict__ A0, const u16* __restrict__ B0,
    const u16* __restrict__ A1, const u16* __restrict__ B1,
    const float* __restrict__ bias0, const float* __restrict__ bias1,
    const float* __restrict__ aux,   // EPI=1: x residual ; EPI=2: Wa3
    void* __restrict__ out,
    long a0z, long oz, int ldo, int aux2 /*EPI<=1: mvalid ; EPI=2: bbase*/, int kiters,
    int mmask, int mshift, int mlimit)
{
  int by = blockIdx.y;
  int m0 = (by & mmask)*128, n0 = (by >> mshift)*128, z = blockIdx.z;
  if(m0 >= mlimit) return;   // block-uniform: safe before barriers

  __shared__ __align__(16) u16 As[128*64];
  __shared__ __align__(16) u16 Bs[128*64];
  int tid = threadIdx.x;

  const u16* Abase0;
  const u16* Bbase0;
  if(AMODE==2){
    Abase0 = (z ? A1 : A0) + (size_t)m0*1024;
    Bbase0 = (z ? B1 : B0) + (size_t)n0*1024;
  } else {
    Abase0 = A0 + (size_t)z*a0z + (size_t)m0*1024;
    Bbase0 = B0 + (size_t)n0*1024;
  }

  f32x4 acc[4][4];
  #pragma unroll
  for(int a=0;a<4;a++)
    #pragma unroll
    for(int b=0;b<4;b++) acc[a][b] = (f32x4){0.f,0.f,0.f,0.f};

  int w = tid>>6, lane = tid&63, quad = lane>>4, l15 = lane&15;
  int wr = (w>>1)*64, wc = (w&1)*64;

  for(int kk=0; kk<kiters; kk++){
    int k0 = (kk & 15) << 6;
    const u16* Ab = Abase0 + k0;
    const u16* Bb = Bbase0 + k0;
    if(AMODE==1 && kk>=16){
      Ab = A1 + (size_t)m0*1024 + k0;
      Bb = B1 + (size_t)n0*1024 + k0;
    }
    __syncthreads();
    stage_gl(Ab, As, tid);
    stage_gl(Bb, Bs, tid);
    __syncthreads();
    #pragma unroll
    for(int kq=0; kq<2; kq++){
      int kbl = kq*4 + quad;
      bf16x8 af[4], bfv[4];
      #pragma unroll
      for(int t=0;t<4;t++){
        int rr = wr + t*16 + l15;
        af[t] = *(const bf16x8*)(As + rr*64 + ((kbl ^ (rr&7))<<3));
      }
      #pragma unroll
      for(int t=0;t<4;t++){
        int cc = wc + t*16 + l15;
        bfv[t] = *(const bf16x8*)(Bs + cc*64 + ((kbl ^ (cc&7))<<3));
      }
      #pragma unroll
      for(int rt=0;rt<4;rt++)
        #pragma unroll
        for(int ct=0;ct<4;ct++)
          acc[rt][ct] = __builtin_amdgcn_mfma_f32_16x16x32_bf16(af[rt], bfv[ct], acc[rt][ct], 0,0,0);
    }
  }

  // per-column constants
  float bc[4], w3[4];
  const float* bsel = (AMODE==2 && z) ? bias1 : bias0;
  #pragma unroll
  for(int ct=0;ct<4;ct++){
    int colg = n0 + wc + ct*16 + l15;
    bc[ct] = bsel[colg];
    if(EPI==1) bc[ct] += bias1[colg];
    if(EPI==2) w3[ct] = aux[colg];
  }

  if(EPI==2){
    float part[4][4];
    #pragma unroll
    for(int rt=0;rt<4;rt++)
      #pragma unroll
      for(int r=0;r<4;r++) part[rt][r] = 0.f;
    #pragma unroll
    for(int rt=0;rt<4;rt++)
      #pragma unroll
      for(int ct=0;ct<4;ct++)
        #pragma unroll
        for(int r=0;r<4;r++)
          part[rt][r] += fmaxf(acc[rt][ct][r] + bc[ct], 0.f) * w3[ct];
    #pragma unroll
    for(int m=1;m<16;m<<=1)
      #pragma unroll
      for(int rt=0;rt<4;rt++)
        #pragma unroll
        for(int r=0;r<4;r++)
          part[rt][r] += __shfl_xor(part[rt][r], m, 64);
    if(l15==0){
      float* lo = (float*)out + (size_t)(aux2 + z)*4096;
      #pragma unroll
      for(int rt=0;rt<4;rt++)
        #pragma unroll
        for(int r=0;r<4;r++)
          atomicAdd(lo + (m0 + wr + rt*16 + quad*4 + r), part[rt][r]);
    }
    return;
  }

  #pragma unroll
  for(int ct=0;ct<4;ct++){
    int colg = n0 + wc + ct*16 + l15;
    #pragma unroll
    for(int rt=0;rt<4;rt++){
      #pragma unroll
      for(int r=0;r<4;r++){
        int rowg = m0 + wr + rt*16 + quad*4 + r;
        float v = acc[rt][ct][r] + bc[ct];
        if(EPI==0){
          v = fmaxf(v, 0.f);
          ((u16*)out)[(size_t)z*oz + (size_t)rowg*ldo + colg] = f2b(v);
        } else {
          if(rowg < aux2){
            v = (v + aux[(size_t)rowg*1024 + colg]) * (1.f/3.f);
            ((float*)out)[(size_t)rowg*ldo + colg] = v;
          }
        }
      }
    }
  }
}

// ---------- AddConv / ModulatorConv aggregation -> a_t, m_t (bf16); sigmoid applied here
__global__ __launch_bounds__(256) void k4_k(const float* __restrict__ x,
    const float* __restrict__ adjA, const float* __restrict__ adjM,
    const float* __restrict__ logit, const float* __restrict__ ba3,
    u16* __restrict__ a_t, u16* __restrict__ m_t)
{
  int b = blockIdx.y, i = blockIdx.x, t = threadIdx.x;
  __shared__ float ca[89], cm[89];
  if(t < 89){
    int tri = (t<=i) ? t*(179-t)/2 + (i-t) : i*(179-i)/2 + (t-i);
    float lg = logit[(size_t)b*4096 + tri] + ba3[0];
    float sv = 1.f/(1.f + expf(-lg));
    ca[t] = sv * adjA[t*89 + i];
    cm[t] = adjM[t*89 + i];
  }
  __syncthreads();
  const float* xb = x + (size_t)b*91136;
  int c0 = t*4;
  float aa0=0,aa1=0,aa2=0,aa3=0, am0=0,am1=0,am2=0,am3=0;
  for(int j=0;j<89;j++){
    float4 xv = *(const float4*)(xb + (size_t)j*1024 + c0);
    float fa=ca[j], fm=cm[j];
    aa0+=fa*xv.x; aa1+=fa*xv.y; aa2+=fa*xv.z; aa3+=fa*xv.w;
    am0+=fm*xv.x; am1+=fm*xv.y; am2+=fm*xv.z; am3+=fm*xv.w;
  }
  float4 xi = *(const float4*)(xb + (size_t)i*1024 + c0);
  size_t ro = ((size_t)(b*89 + i))*1024 + c0;
  ushort4 oa; oa.x=f2b(aa0); oa.y=f2b(aa1); oa.z=f2b(aa2); oa.w=f2b(aa3);
  ushort4 om;
  om.x=f2b(xi.x*am0); om.y=f2b(xi.y*am1);
  om.z=f2b(xi.z*am2); om.w=f2b(xi.w*am3);
  *(ushort4*)(a_t + ro) = oa;
  *(ushort4*)(m_t + ro) = om;
}

extern "C" void kernel_launch(void* const* d_in, const int* in_sizes, int n_in,
                              void* d_out, int out_size, void* d_ws, size_t ws_size,
                              hipStream_t stream)
{
  const float* X     = (const float*)d_in[0];
  const float* adjA  = (const float*)d_in[1];
  const float* adjM  = (const float*)d_in[2];
  const float* Wa1   = (const float*)d_in[3];
  const float* ba1   = (const float*)d_in[4];
  const float* Wa2   = (const float*)d_in[5];
  const float* ba2   = (const float*)d_in[6];
  const float* Wa3   = (const float*)d_in[7];
  const float* ba3   = (const float*)d_in[8];
  const float* Wadd1 = (const float*)d_in[9];
  const float* badd1 = (const float*)d_in[10];
  const float* Wadd2 = (const float*)d_in[11];
  const float* badd2 = (const float*)d_in[12];
  const float* Wmod1 = (const float*)d_in[13];
  const float* bmod1 = (const float*)d_in[14];
  const float* Wmod2 = (const float*)d_in[15];
  const float* bmod2 = (const float*)d_in[16];

  char* w = (char*)d_ws;
  u16* WaT1   = (u16*)w; w += (size_t)1024*1024*2;
  u16* WaT2   = (u16*)w; w += (size_t)512*1024*2;
  u16* WaddT1 = (u16*)w; w += (size_t)1024*1024*2;
  u16* WaddT2 = (u16*)w; w += (size_t)1024*1024*2;
  u16* WmodT1 = (u16*)w; w += (size_t)1024*1024*2;
  u16* WmodT2 = (u16*)w; w += (size_t)1024*1024*2;
  float* logit= (float*)w; w += (size_t)8*4096*4;
  u16* a_t    = (u16*)w; w += (size_t)768*1024*2;
  u16* m_t    = (u16*)w; w += (size_t)768*1024*2;
  u16* ha     = (u16*)w; w += (size_t)768*1024*2;
  u16* hm     = (u16*)w; w += (size_t)768*1024*2;   // must stay adjacent to ha
  size_t fixed = (size_t)(w - (char*)d_ws);
  size_t per_p = (size_t)4096*1024*2, per_h1 = (size_t)4096*1024*2;
  bool flat = ws_size >= fixed + 8*(per_p + per_h1);
  int nb = flat ? 8 : 1;
  u16* pbuf = (u16*)w; w += per_p  * nb;
  u16* h1   = (u16*)w;

  TrPack tp;
  tp.a[0].src = Wa1;   tp.a[0].dst = WaT1;   tp.a[0].C = 1024;
  tp.a[1].src = Wa2;   tp.a[1].dst = WaT2;   tp.a[1].C = 512;
  tp.a[2].src = Wadd1; tp.a[2].dst = WaddT1; tp.a[2].C = 1024;
  tp.a[3].src = Wadd2; tp.a[3].dst = WaddT2; tp.a[3].C = 1024;
  tp.a[4].src = Wmod1; tp.a[4].dst = WmodT1; tp.a[4].C = 1024;
  tp.a[5].src = Wmod2; tp.a[5].dst = WmodT2; tp.a[5].C = 1024;

  long pz = 4096*1024, h1z = 4096*1024;
  prep_k<<<dim3(6176 + 4096*nb), 256, 0, stream>>>(tp, logit, X, pbuf, pz);

  for(int bb=0; bb<8; bb+=nb){
    if(bb) pgen_k<<<dim3(4096,nb),256,0,stream>>>(X, pbuf, pz, bb);
    // layer1: M=4096 (32 mblk), N=1024 (8 nblk): y = n*32 + m
    gemm_k<0,0><<<dim3(1,256,nb),256,0,stream>>>(pbuf, WaT1, nullptr,nullptr, ba1,nullptr, nullptr,
                                                 h1, pz, h1z, 1024, 4096, 16, 31, 5, 4096);
    // layer2 + logit epilogue: M=4096 (32 mblk), N=512 (4 nblk)
    gemm_k<0,2><<<dim3(1,128,nb),256,0,stream>>>(h1, WaT2, nullptr,nullptr, ba2,nullptr, Wa3,
                                                 logit, h1z, 0, 0, bb, 16, 31, 5, 4096);
  }
  k4_k<<<dim3(89,8),256,0,stream>>>(X, adjA, adjM, logit, ba3, a_t, m_t);
  // merged tail GEMMs: z=0 -> a_t@Wadd1 -> ha ; z=1 -> m_t@Wmod1 -> hm (= ha + 768*1024)
  gemm_k<2,0><<<dim3(1,64,2),256,0,stream>>>(a_t, WaddT1, m_t, WmodT1, badd1, bmod1, nullptr,
                                             ha, 0, (long)768*1024, 1024, 768, 16, 7, 3, 768);
  gemm_k<1,1><<<dim3(1,64,1),256,0,stream>>>(ha, WaddT2, hm, WmodT2, badd2, bmod2, X,
                                             (float*)d_out, 0, 0, 1024, 712, 32, 7, 3, 768);
}

// Round 5
// 299.010 us; speedup vs baseline: 1.3959x; 1.0634x over previous
//
#include <hip/hip_runtime.h>

typedef unsigned short u16;
typedef unsigned int   u32;
typedef __attribute__((ext_vector_type(8))) short bf16x8;
typedef __attribute__((ext_vector_type(4))) float f32x4;

#define DEVFN __device__ __forceinline__

DEVFN float b2f(u16 u){ u32 t=((u32)u)<<16; float f; __builtin_memcpy(&f,&t,4); return f; }
DEVFN u16 f2b(float f){ u32 t; __builtin_memcpy(&t,&f,4); t += 0x7fffu + ((t>>16)&1u); return (u16)(t>>16); }

// row -> (j,i) for upper-triangle pairs j<=i, N=89; base(j) = j*(179-j)/2
DEVFN void row2ji(int row, int* jj, int* ii){
  int j = (int)((179.0f - sqrtf(179.0f*179.0f - 8.0f*(float)row)) * 0.5f);
  if(j < 0) j = 0; if(j > 88) j = 88;
  while(j < 88 && (j+1)*(179-(j+1))/2 <= row) j++;
  while(j > 0 && j*(179-j)/2 > row) j--;
  *jj = j;
  *ii = j + (row - j*(179-j)/2);
}

struct TrArgs { const float* src; u16* dst; int C; };
struct TrPack { TrArgs a[6]; };

// pgen body: p[row,:] = bf16(x[b,j,:]*x[b,i,:])
DEVFN void pgen_body(const float* __restrict__ x, u16* __restrict__ p, long pz,
                     int z, int b, int row, int tid){
  int j, i; row2ji(row < 4005 ? row : 0, &j, &i);
  const float* xb = x + (size_t)b*91136;  // 89*1024
  int c = tid*4;
  float4 a  = *(const float4*)(xb + (size_t)j*1024 + c);
  float4 bb = *(const float4*)(xb + (size_t)i*1024 + c);
  ushort4 o;
  o.x = f2b(a.x*bb.x);
  o.y = f2b(a.y*bb.y);
  o.z = f2b(a.z*bb.z);
  o.w = f2b(a.w*bb.w);
  *(ushort4*)(p + (size_t)z*pz + (size_t)row*1024 + c) = o;
}

// ---------- fused prep: [0,6144) weight transposes, [6144,6176) logit zero,
//                        [6176,6176+4096*nb) pgen for batches 0..nb-1
__global__ __launch_bounds__(256) void prep_k(TrPack pk, float* __restrict__ logit,
                                              const float* __restrict__ x,
                                              u16* __restrict__ pbuf, long pz){
  __shared__ u16 tile[32][33];
  int id = blockIdx.x, tid = threadIdx.x;
  if(id < 6144){
    TrArgs t = pk.a[id>>10];
    int q = id & 1023;
    int bx = (q&31)*32, by = (q>>5)*32;
    if(bx >= t.C) return;
    int tx = tid&31, ty = tid>>5;
    #pragma unroll
    for(int yy=ty; yy<32; yy+=8) tile[yy][tx] = f2b(t.src[(size_t)(by+yy)*t.C + bx+tx]);
    __syncthreads();
    #pragma unroll
    for(int yy=ty; yy<32; yy+=8) t.dst[(size_t)(bx+yy)*1024 + by+tx] = tile[tx][yy];
  } else if(id < 6176){
    int idx = (id-6144)*1024 + tid*4;
    *(float4*)(logit + idx) = (float4){0.f,0.f,0.f,0.f};
  } else {
    int pid = id - 6176;
    int z = pid >> 12, row = pid & 4095;
    pgen_body(x, pbuf, pz, z, z, row, tid);   // bbase = 0 for prep
  }
}

// standalone pgen for per-batch fallback iterations
__global__ __launch_bounds__(256) void pgen_k(const float* __restrict__ x,
                                              u16* __restrict__ p, long pz, int bbase){
  pgen_body(x, p, pz, blockIdx.y, bbase + blockIdx.y, blockIdx.x, threadIdx.x);
}

// ---------- staging: ROWS x 64 k (bf16) via global_load_lds, XOR-swizzled k-blocks
template<int ROWS>
DEVFN void stage_gl(const u16* __restrict__ g0, u16* lds0, int tid){
  constexpr int IT = ROWS/32;           // 16B slots = ROWS*8; per-thread = ROWS/32
  int w = tid>>6, lane = tid&63;
  #pragma unroll
  for(int i=0;i<IT;i++){
    int p  = (w*IT+i)*64 + lane;
    int r  = p>>3;
    int kb = (p&7) ^ (r&7);
    const u16* g = g0 + ((size_t)r<<10) + (kb<<3);
    u16* l = lds0 + (size_t)(w*IT+i)*512;
    __builtin_amdgcn_global_load_lds((const __attribute__((address_space(1))) u32*)g,
                                     (__attribute__((address_space(3))) u32*)l, 16, 0, 0);
  }
}

// ---------- GEMM: tiles TMx128, BK=64, 4 waves; blockIdx.y = n*mblkpad + m
// AMODE: 0 = single source (z = batch, A += z*a0z) ; 2 = z-select (z? A1,B1,bias1 : A0,B0,bias0)
// EPI:   0 = relu+bias -> bf16 out (+z*oz), LDS-staged coalesced write
//        2 = logit: relu+bias tile dot aux(=Wa3), lane-reduced, atomicAdd ((float*)out)[(aux2+z)*4096+row]
//        3 = split-K final: atomicAdd fp32 acc/3 into out; z==0 also adds (aux(x)+bias0+bias1)/3; row<712 guard
template<int AMODE, int EPI, int TM>
__global__ __launch_bounds__(256,2) void gemm_k(
    const u16* __restrict__ A0, const u16* __restrict__ B0,
    const u16* __restrict__ A1, const u16* __restrict__ B1,
    const float* __restrict__ bias0, const float* __restrict__ bias1,
    const float* __restrict__ aux,   // EPI=2: Wa3 ; EPI=3: x residual
    void* __restrict__ out,
    long a0z, long oz, int ldo, int aux2 /*EPI=2: bbase ; EPI=3: mvalid*/, int kiters,
    int mmask, int mshift, int mlimit)
{
  constexpr int MB = TM/32;            // row frags per wave (128->4, 64->2)
  int by = blockIdx.y;
  int m0 = (by & mmask)*TM, n0 = (by >> mshift)*128, z = blockIdx.z;
  if(m0 >= mlimit) return;   // block-uniform: safe before barriers

  __shared__ __align__(16) u16 smem[TM*64 + 128*64];
  u16* As = smem;
  u16* Bs = smem + TM*64;
  int tid = threadIdx.x;

  const u16* Abase0;
  const u16* Bbase0;
  if(AMODE==2){
    Abase0 = (z ? A1 : A0) + (size_t)m0*1024;
    Bbase0 = (z ? B1 : B0) + (size_t)n0*1024;
  } else {
    Abase0 = A0 + (size_t)z*a0z + (size_t)m0*1024;
    Bbase0 = B0 + (size_t)n0*1024;
  }

  f32x4 acc[MB][4];
  #pragma unroll
  for(int a=0;a<MB;a++)
    #pragma unroll
    for(int b=0;b<4;b++) acc[a][b] = (f32x4){0.f,0.f,0.f,0.f};

  int w = tid>>6, lane = tid&63, quad = lane>>4, l15 = lane&15;
  int wr = (w>>1)*(TM/2), wc = (w&1)*64;

  for(int kk=0; kk<kiters; kk++){
    int k0 = (kk & 15) << 6;
    const u16* Ab = Abase0 + k0;
    const u16* Bb = Bbase0 + k0;
    __syncthreads();
    stage_gl<TM >(Ab, As, tid);
    stage_gl<128>(Bb, Bs, tid);
    __syncthreads();
    #pragma unroll
    for(int kq=0; kq<2; kq++){
      int kbl = kq*4 + quad;
      bf16x8 af[MB], bfv[4];
      #pragma unroll
      for(int t=0;t<MB;t++){
        int rr = wr + t*16 + l15;
        af[t] = *(const bf16x8*)(As + rr*64 + ((kbl ^ (rr&7))<<3));
      }
      #pragma unroll
      for(int t=0;t<4;t++){
        int cc = wc + t*16 + l15;
        bfv[t] = *(const bf16x8*)(Bs + cc*64 + ((kbl ^ (cc&7))<<3));
      }
      #pragma unroll
      for(int rt=0;rt<MB;rt++)
        #pragma unroll
        for(int ct=0;ct<4;ct++)
          acc[rt][ct] = __builtin_amdgcn_mfma_f32_16x16x32_bf16(af[rt], bfv[ct], acc[rt][ct], 0,0,0);
    }
  }

  // per-column constants
  float bc[4], w3[4];
  #pragma unroll
  for(int ct=0;ct<4;ct++){
    int colg = n0 + wc + ct*16 + l15;
    if(EPI==3){
      bc[ct] = (z==0) ? (bias0[colg] + bias1[colg]) : 0.f;
    } else {
      bc[ct] = (AMODE==2 && z) ? bias1[colg] : bias0[colg];
      if(EPI==2) w3[ct] = aux[colg];
    }
  }

  if(EPI==2){
    float part[MB][4];
    #pragma unroll
    for(int rt=0;rt<MB;rt++)
      #pragma unroll
      for(int r=0;r<4;r++) part[rt][r] = 0.f;
    #pragma unroll
    for(int rt=0;rt<MB;rt++)
      #pragma unroll
      for(int ct=0;ct<4;ct++)
        #pragma unroll
        for(int r=0;r<4;r++)
          part[rt][r] += fmaxf(acc[rt][ct][r] + bc[ct], 0.f) * w3[ct];
    #pragma unroll
    for(int m=1;m<16;m<<=1)
      #pragma unroll
      for(int rt=0;rt<MB;rt++)
        #pragma unroll
        for(int r=0;r<4;r++)
          part[rt][r] += __shfl_xor(part[rt][r], m, 64);
    if(l15==0){
      float* lo = (float*)out + (size_t)(aux2 + z)*4096;
      #pragma unroll
      for(int rt=0;rt<MB;rt++)
        #pragma unroll
        for(int r=0;r<4;r++)
          atomicAdd(lo + (m0 + wr + rt*16 + quad*4 + r), part[rt][r]);
    }
    return;
  }

  if(EPI==3){
    const float third = 1.f/3.f;
    float* op = (float*)out;
    #pragma unroll
    for(int ct=0;ct<4;ct++){
      int colg = n0 + wc + ct*16 + l15;
      #pragma unroll
      for(int rt=0;rt<MB;rt++){
        #pragma unroll
        for(int r=0;r<4;r++){
          int rowg = m0 + wr + rt*16 + quad*4 + r;
          if(rowg < aux2){
            float v = acc[rt][ct][r];
            if(z==0) v += aux[(size_t)rowg*1024 + colg] + bc[ct];
            atomicAdd(op + (size_t)rowg*1024 + colg, v*third);
          }
        }
      }
    }
    return;
  }

  // EPI==0: stage C tile (TM x 128 bf16) in LDS, then coalesced 16B stores
  __syncthreads();               // all waves done reading As/Bs
  u16* Ct = smem;
  #pragma unroll
  for(int ct=0;ct<4;ct++){
    int cl = wc + ct*16 + l15;
    #pragma unroll
    for(int rt=0;rt<MB;rt++){
      #pragma unroll
      for(int r=0;r<4;r++){
        int rl = wr + rt*16 + quad*4 + r;
        Ct[rl*128 + cl] = f2b(fmaxf(acc[rt][ct][r] + bc[ct], 0.f));
      }
    }
  }
  __syncthreads();
  u16* outp = (u16*)out + (size_t)z*oz;
  #pragma unroll
  for(int i=0;i<TM/16;i++){
    int q = i*256 + tid;         // 16B chunk id, TM*16 total
    int row = q>>4, c16 = q&15;
    *(uint4*)(outp + (size_t)(m0+row)*ldo + n0 + c16*8) = *(const uint4*)(Ct + row*128 + c16*8);
  }
}

// ---------- AddConv / ModulatorConv aggregation -> a_t, m_t (bf16); sigmoid applied here
__global__ __launch_bounds__(256) void k4_k(const float* __restrict__ x,
    const float* __restrict__ adjA, const float* __restrict__ adjM,
    const float* __restrict__ logit, const float* __restrict__ ba3,
    u16* __restrict__ a_t, u16* __restrict__ m_t)
{
  int b = blockIdx.y, i = blockIdx.x, t = threadIdx.x;
  __shared__ float ca[89], cm[89];
  if(t < 89){
    int tri = (t<=i) ? t*(179-t)/2 + (i-t) : i*(179-i)/2 + (t-i);
    float lg = logit[(size_t)b*4096 + tri] + ba3[0];
    float sv = 1.f/(1.f + expf(-lg));
    ca[t] = sv * adjA[t*89 + i];
    cm[t] = adjM[t*89 + i];
  }
  __syncthreads();
  const float* xb = x + (size_t)b*91136;
  int c0 = t*4;
  float aa0=0,aa1=0,aa2=0,aa3=0, am0=0,am1=0,am2=0,am3=0;
  for(int j=0;j<89;j++){
    float4 xv = *(const float4*)(xb + (size_t)j*1024 + c0);
    float fa=ca[j], fm=cm[j];
    aa0+=fa*xv.x; aa1+=fa*xv.y; aa2+=fa*xv.z; aa3+=fa*xv.w;
    am0+=fm*xv.x; am1+=fm*xv.y; am2+=fm*xv.z; am3+=fm*xv.w;
  }
  float4 xi = *(const float4*)(xb + (size_t)i*1024 + c0);
  size_t ro = ((size_t)(b*89 + i))*1024 + c0;
  ushort4 oa; oa.x=f2b(aa0); oa.y=f2b(aa1); oa.z=f2b(aa2); oa.w=f2b(aa3);
  ushort4 om;
  om.x=f2b(xi.x*am0); om.y=f2b(xi.y*am1);
  om.z=f2b(xi.z*am2); om.w=f2b(xi.w*am3);
  *(ushort4*)(a_t + ro) = oa;
  *(ushort4*)(m_t + ro) = om;
}

extern "C" void kernel_launch(void* const* d_in, const int* in_sizes, int n_in,
                              void* d_out, int out_size, void* d_ws, size_t ws_size,
                              hipStream_t stream)
{
  const float* X     = (const float*)d_in[0];
  const float* adjA  = (const float*)d_in[1];
  const float* adjM  = (const float*)d_in[2];
  const float* Wa1   = (const float*)d_in[3];
  const float* ba1   = (const float*)d_in[4];
  const float* Wa2   = (const float*)d_in[5];
  const float* ba2   = (const float*)d_in[6];
  const float* Wa3   = (const float*)d_in[7];
  const float* ba3   = (const float*)d_in[8];
  const float* Wadd1 = (const float*)d_in[9];
  const float* badd1 = (const float*)d_in[10];
  const float* Wadd2 = (const float*)d_in[11];
  const float* badd2 = (const float*)d_in[12];
  const float* Wmod1 = (const float*)d_in[13];
  const float* bmod1 = (const float*)d_in[14];
  const float* Wmod2 = (const float*)d_in[15];
  const float* bmod2 = (const float*)d_in[16];

  char* w = (char*)d_ws;
  u16* WaT1   = (u16*)w; w += (size_t)1024*1024*2;
  u16* WaT2   = (u16*)w; w += (size_t)512*1024*2;
  u16* WaddT1 = (u16*)w; w += (size_t)1024*1024*2;
  u16* WaddT2 = (u16*)w; w += (size_t)1024*1024*2;
  u16* WmodT1 = (u16*)w; w += (size_t)1024*1024*2;
  u16* WmodT2 = (u16*)w; w += (size_t)1024*1024*2;
  float* logit= (float*)w; w += (size_t)8*4096*4;
  u16* a_t    = (u16*)w; w += (size_t)768*1024*2;
  u16* m_t    = (u16*)w; w += (size_t)768*1024*2;
  u16* ha     = (u16*)w; w += (size_t)768*1024*2;
  u16* hm     = (u16*)w; w += (size_t)768*1024*2;   // must stay adjacent to ha
  size_t fixed = (size_t)(w - (char*)d_ws);
  size_t per_p = (size_t)4096*1024*2, per_h1 = (size_t)4096*1024*2;
  bool flat = ws_size >= fixed + 8*(per_p + per_h1);
  int nb = flat ? 8 : 1;
  u16* pbuf = (u16*)w; w += per_p  * nb;
  u16* h1   = (u16*)w;

  TrPack tp;
  tp.a[0].src = Wa1;   tp.a[0].dst = WaT1;   tp.a[0].C = 1024;
  tp.a[1].src = Wa2;   tp.a[1].dst = WaT2;   tp.a[1].C = 512;
  tp.a[2].src = Wadd1; tp.a[2].dst = WaddT1; tp.a[2].C = 1024;
  tp.a[3].src = Wadd2; tp.a[3].dst = WaddT2; tp.a[3].C = 1024;
  tp.a[4].src = Wmod1; tp.a[4].dst = WmodT1; tp.a[4].C = 1024;
  tp.a[5].src = Wmod2; tp.a[5].dst = WmodT2; tp.a[5].C = 1024;

  long pz = 4096*1024, h1z = 4096*1024;
  prep_k<<<dim3(6176 + 4096*nb), 256, 0, stream>>>(tp, logit, X, pbuf, pz);

  for(int bb=0; bb<8; bb+=nb){
    if(bb) pgen_k<<<dim3(4096,nb),256,0,stream>>>(X, pbuf, pz, bb);
    // layer1: M=4096 (32 mblk), N=1024 (8 nblk): y = n*32 + m
    gemm_k<0,0,128><<<dim3(1,256,nb),256,0,stream>>>(pbuf, WaT1, nullptr,nullptr, ba1,nullptr, nullptr,
                                                     h1, pz, h1z, 1024, 4096, 16, 31, 5, 4096);
    // layer2 + logit epilogue: M=4096 (32 mblk), N=512 (4 nblk)
    gemm_k<0,2,128><<<dim3(1,128,nb),256,0,stream>>>(h1, WaT2, nullptr,nullptr, ba2,nullptr, Wa3,
                                                     logit, h1z, 0, 0, bb, 16, 31, 5, 4096);
  }
  k4_k<<<dim3(89,8),256,0,stream>>>(X, adjA, adjM, logit, ba3, a_t, m_t);
  // tail hidden GEMMs (TM=64): z=0 -> a_t@Wadd1 -> ha ; z=1 -> m_t@Wmod1 -> hm
  // M=768 -> 12 mblk padded to 16 (mmask=15, mshift=4), N=1024 -> 8 nblk
  gemm_k<2,0,64><<<dim3(1,128,2),256,0,stream>>>(a_t, WaddT1, m_t, WmodT1, badd1, bmod1, nullptr,
                                                 ha, 0, (long)768*1024, 1024, 768, 16, 15, 4, 768);
  // final split-K (TM=64): d_out zeroed, z=0: ha@WaddT2 (+x+biases)/3, z=1: hm@WmodT2 /3
  hipMemsetAsync(d_out, 0, (size_t)out_size*4, stream);
  gemm_k<2,3,64><<<dim3(1,128,2),256,0,stream>>>(ha, WaddT2, hm, WmodT2, badd2, bmod2, X,
                                                 d_out, 0, 0, 1024, 712, 16, 15, 4, 768);
}

// Round 6
// 272.381 us; speedup vs baseline: 1.5324x; 1.0978x over previous
//
#include <hip/hip_runtime.h>

typedef unsigned short u16;
typedef unsigned int   u32;
typedef __attribute__((ext_vector_type(8))) short bf16x8;
typedef __attribute__((ext_vector_type(4))) float f32x4;

#define DEVFN __device__ __forceinline__

DEVFN float b2f(u16 u){ u32 t=((u32)u)<<16; float f; __builtin_memcpy(&f,&t,4); return f; }
DEVFN u16 f2b(float f){ u32 t; __builtin_memcpy(&t,&f,4); t += 0x7fffu + ((t>>16)&1u); return (u16)(t>>16); }
DEVFN u32 pk2(float a, float b){ return (u32)f2b(a) | ((u32)f2b(b)<<16); }

// row -> (j,i) for upper-triangle pairs j<=i, N=89; base(j) = j*(179-j)/2
DEVFN void row2ji(int row, int* jj, int* ii){
  int j = (int)((179.0f - sqrtf(179.0f*179.0f - 8.0f*(float)row)) * 0.5f);
  if(j < 0) j = 0; if(j > 88) j = 88;
  while(j < 88 && (j+1)*(179-(j+1))/2 <= row) j++;
  while(j > 0 && j*(179-j)/2 > row) j--;
  *jj = j;
  *ii = j + (row - j*(179-j)/2);
}

struct TrArgs { const float* src; u16* dst; int C; };
struct TrPack { TrArgs a[6]; };

// ---------- fused prep:
// [0,6144)        weight transposes (32x32 tiles)
// [6144,6176)     logit zero (8*4096 fp32)
// [6176,6888)     d_out zero (712*1024 fp32)
// [6888,6888+2048*nb) pgen pairs: 2 rows per block, 16B stores
__global__ __launch_bounds__(256) void prep_k(TrPack pk, float* __restrict__ logit,
                                              float* __restrict__ dout,
                                              const float* __restrict__ x,
                                              u16* __restrict__ pbuf, long pz){
  __shared__ u16 tile[32][33];
  int id = blockIdx.x, tid = threadIdx.x;
  if(id < 6144){
    TrArgs t = pk.a[id>>10];
    int q = id & 1023;
    int bx = (q&31)*32, by = (q>>5)*32;
    if(bx >= t.C) return;
    int tx = tid&31, ty = tid>>5;
    #pragma unroll
    for(int yy=ty; yy<32; yy+=8) tile[yy][tx] = f2b(t.src[(size_t)(by+yy)*t.C + bx+tx]);
    __syncthreads();
    #pragma unroll
    for(int yy=ty; yy<32; yy+=8) t.dst[(size_t)(bx+yy)*1024 + by+tx] = tile[tx][yy];
  } else if(id < 6176){
    int idx = (id-6144)*1024 + tid*4;
    *(float4*)(logit + idx) = (float4){0.f,0.f,0.f,0.f};
  } else if(id < 6888){
    int idx = (id-6176)*1024 + tid*4;
    *(float4*)(dout + idx) = (float4){0.f,0.f,0.f,0.f};
  } else {
    int pid = id - 6888;
    int z = pid >> 11, rp = pid & 2047;
    int half = tid >> 7, t7 = tid & 127;
    int row = rp*2 + half;
    int j, i; row2ji(row < 4005 ? row : 0, &j, &i);
    const float* xb = x + (size_t)z*91136;
    int c = t7*8;
    float4 a0 = *(const float4*)(xb + (size_t)j*1024 + c);
    float4 a1 = *(const float4*)(xb + (size_t)j*1024 + c + 4);
    float4 b0 = *(const float4*)(xb + (size_t)i*1024 + c);
    float4 b1 = *(const float4*)(xb + (size_t)i*1024 + c + 4);
    uint4 o;
    o.x = pk2(a0.x*b0.x, a0.y*b0.y);
    o.y = pk2(a0.z*b0.z, a0.w*b0.w);
    o.z = pk2(a1.x*b1.x, a1.y*b1.y);
    o.w = pk2(a1.z*b1.z, a1.w*b1.w);
    *(uint4*)(pbuf + (size_t)z*pz + (size_t)row*1024 + c) = o;
  }
}

// standalone pgen for per-batch fallback iterations (1 row per block)
__global__ __launch_bounds__(256) void pgen_k(const float* __restrict__ x,
                                              u16* __restrict__ p, long pz, int bbase){
  int z = blockIdx.y, b = bbase + z, row = blockIdx.x;
  int j, i; row2ji(row < 4005 ? row : 0, &j, &i);
  const float* xb = x + (size_t)b*91136;
  int c = threadIdx.x*4;
  float4 a  = *(const float4*)(xb + (size_t)j*1024 + c);
  float4 bb = *(const float4*)(xb + (size_t)i*1024 + c);
  ushort4 o;
  o.x = f2b(a.x*bb.x); o.y = f2b(a.y*bb.y);
  o.z = f2b(a.z*bb.z); o.w = f2b(a.w*bb.w);
  *(ushort4*)(p + (size_t)z*pz + (size_t)row*1024 + c) = o;
}

// ---------- staging: ROWS x 64 k (bf16) via global_load_lds, XOR-swizzled k-blocks
template<int ROWS>
DEVFN void stage_gl(const u16* __restrict__ g0, u16* lds0, int tid){
  constexpr int IT = ROWS/32;
  int w = tid>>6, lane = tid&63;
  #pragma unroll
  for(int i=0;i<IT;i++){
    int p  = (w*IT+i)*64 + lane;
    int r  = p>>3;
    int kb = (p&7) ^ (r&7);
    const u16* g = g0 + ((size_t)r<<10) + (kb<<3);
    u16* l = lds0 + (size_t)(w*IT+i)*512;
    __builtin_amdgcn_global_load_lds((const __attribute__((address_space(1))) u32*)g,
                                     (__attribute__((address_space(3))) u32*)l, 16, 0, 0);
  }
}

// ---------- GEMM: tiles TMxTN, BK=64, 4 waves (2x2); blockIdx.y = n*mblkpad + m
// AMODE: 0 = single source (z = batch, A += z*a0z) ; 2 = z-select (z? A1,B1,bias1 : A0,B0,bias0)
// EPI:   0 = relu+bias -> bf16 out (+z*oz), LDS-staged coalesced write
//        2 = logit: relu+bias tile dot aux(=Wa3), lane-reduced, atomicAdd ((float*)out)[(aux2+z)*4096+row]
//        3 = split-K final: atomicAdd fp32 acc/3 into out; z==0 also adds (aux(x)+bias0+bias1)/3; row<aux2 guard
template<int AMODE, int EPI, int TM, int TN>
__global__ __launch_bounds__(256,2) void gemm_k(
    const u16* __restrict__ A0, const u16* __restrict__ B0,
    const u16* __restrict__ A1, const u16* __restrict__ B1,
    const float* __restrict__ bias0, const float* __restrict__ bias1,
    const float* __restrict__ aux,
    void* __restrict__ out,
    long a0z, long oz, int ldo, int aux2, int kiters,
    int mmask, int mshift, int mlimit)
{
  constexpr int MB = TM/32, NB = TN/32;
  int by = blockIdx.y;
  int m0 = (by & mmask)*TM, n0 = (by >> mshift)*TN, z = blockIdx.z;
  if(m0 >= mlimit) return;   // block-uniform: safe before barriers

  __shared__ __align__(16) u16 smem[TM*64 + TN*64];
  u16* As = smem;
  u16* Bs = smem + TM*64;
  int tid = threadIdx.x;

  const u16* Abase0;
  const u16* Bbase0;
  if(AMODE==2){
    Abase0 = (z ? A1 : A0) + (size_t)m0*1024;
    Bbase0 = (z ? B1 : B0) + (size_t)n0*1024;
  } else {
    Abase0 = A0 + (size_t)z*a0z + (size_t)m0*1024;
    Bbase0 = B0 + (size_t)n0*1024;
  }

  f32x4 acc[MB][NB];
  #pragma unroll
  for(int a=0;a<MB;a++)
    #pragma unroll
    for(int b=0;b<NB;b++) acc[a][b] = (f32x4){0.f,0.f,0.f,0.f};

  int w = tid>>6, lane = tid&63, quad = lane>>4, l15 = lane&15;
  int wr = (w>>1)*(TM/2), wc = (w&1)*(TN/2);

  for(int kk=0; kk<kiters; kk++){
    int k0 = (kk & 15) << 6;
    const u16* Ab = Abase0 + k0;
    const u16* Bb = Bbase0 + k0;
    __syncthreads();
    stage_gl<TM>(Ab, As, tid);
    stage_gl<TN>(Bb, Bs, tid);
    __syncthreads();
    #pragma unroll
    for(int kq=0; kq<2; kq++){
      int kbl = kq*4 + quad;
      bf16x8 af[MB], bfv[NB];
      #pragma unroll
      for(int t=0;t<MB;t++){
        int rr = wr + t*16 + l15;
        af[t] = *(const bf16x8*)(As + rr*64 + ((kbl ^ (rr&7))<<3));
      }
      #pragma unroll
      for(int t=0;t<NB;t++){
        int cc = wc + t*16 + l15;
        bfv[t] = *(const bf16x8*)(Bs + cc*64 + ((kbl ^ (cc&7))<<3));
      }
      #pragma unroll
      for(int rt=0;rt<MB;rt++)
        #pragma unroll
        for(int ct=0;ct<NB;ct++)
          acc[rt][ct] = __builtin_amdgcn_mfma_f32_16x16x32_bf16(af[rt], bfv[ct], acc[rt][ct], 0,0,0);
    }
  }

  float bc[NB], w3[NB];
  #pragma unroll
  for(int ct=0;ct<NB;ct++){
    int colg = n0 + wc + ct*16 + l15;
    if(EPI==3){
      bc[ct] = (z==0) ? (bias0[colg] + bias1[colg]) : 0.f;
    } else {
      bc[ct] = (AMODE==2 && z) ? bias1[colg] : bias0[colg];
      if(EPI==2) w3[ct] = aux[colg];
    }
  }

  if(EPI==2){
    float part[MB][4];
    #pragma unroll
    for(int rt=0;rt<MB;rt++)
      #pragma unroll
      for(int r=0;r<4;r++) part[rt][r] = 0.f;
    #pragma unroll
    for(int rt=0;rt<MB;rt++)
      #pragma unroll
      for(int ct=0;ct<NB;ct++)
        #pragma unroll
        for(int r=0;r<4;r++)
          part[rt][r] += fmaxf(acc[rt][ct][r] + bc[ct], 0.f) * w3[ct];
    #pragma unroll
    for(int m=1;m<16;m<<=1)
      #pragma unroll
      for(int rt=0;rt<MB;rt++)
        #pragma unroll
        for(int r=0;r<4;r++)
          part[rt][r] += __shfl_xor(part[rt][r], m, 64);
    if(l15==0){
      float* lo = (float*)out + (size_t)(aux2 + z)*4096;
      #pragma unroll
      for(int rt=0;rt<MB;rt++)
        #pragma unroll
        for(int r=0;r<4;r++)
          atomicAdd(lo + (m0 + wr + rt*16 + quad*4 + r), part[rt][r]);
    }
    return;
  }

  if(EPI==3){
    const float third = 1.f/3.f;
    float* op = (float*)out;
    #pragma unroll
    for(int ct=0;ct<NB;ct++){
      int colg = n0 + wc + ct*16 + l15;
      #pragma unroll
      for(int rt=0;rt<MB;rt++){
        #pragma unroll
        for(int r=0;r<4;r++){
          int rowg = m0 + wr + rt*16 + quad*4 + r;
          if(rowg < aux2){
            float v = acc[rt][ct][r];
            if(z==0) v += aux[(size_t)rowg*1024 + colg] + bc[ct];
            atomicAdd(op + (size_t)rowg*ldo + colg, v*third);
          }
        }
      }
    }
    return;
  }

  // EPI==0: stage C tile (TM x TN bf16) in LDS, then coalesced 16B stores
  __syncthreads();
  u16* Ct = smem;
  #pragma unroll
  for(int ct=0;ct<NB;ct++){
    int cl = wc + ct*16 + l15;
    #pragma unroll
    for(int rt=0;rt<MB;rt++){
      #pragma unroll
      for(int r=0;r<4;r++){
        int rl = wr + rt*16 + quad*4 + r;
        Ct[rl*TN + cl] = f2b(fmaxf(acc[rt][ct][r] + bc[ct], 0.f));
      }
    }
  }
  __syncthreads();
  u16* outp = (u16*)out + (size_t)z*oz;
  #pragma unroll
  for(int i=0;i<TM*TN/2048;i++){
    int q = i*256 + tid;
    int row = q/(TN/8), c16 = q%(TN/8);
    *(uint4*)(outp + (size_t)(m0+row)*ldo + n0 + c16*8) = *(const uint4*)(Ct + row*TN + c16*8);
  }
}

// ---------- AddConv / ModulatorConv aggregation -> a_t, m_t (bf16); sigmoid applied here
__global__ __launch_bounds__(256) void k4_k(const float* __restrict__ x,
    const float* __restrict__ adjA, const float* __restrict__ adjM,
    const float* __restrict__ logit, const float* __restrict__ ba3,
    u16* __restrict__ a_t, u16* __restrict__ m_t)
{
  int b = blockIdx.y, i = blockIdx.x, t = threadIdx.x;
  __shared__ float ca[89], cm[89];
  if(t < 89){
    int tri = (t<=i) ? t*(179-t)/2 + (i-t) : i*(179-i)/2 + (t-i);
    float lg = logit[(size_t)b*4096 + tri] + ba3[0];
    float sv = 1.f/(1.f + expf(-lg));
    ca[t] = sv * adjA[t*89 + i];
    cm[t] = adjM[t*89 + i];
  }
  __syncthreads();
  const float* xb = x + (size_t)b*91136;
  int c0 = t*4;
  float aa0=0,aa1=0,aa2=0,aa3=0, am0=0,am1=0,am2=0,am3=0;
  #pragma unroll 8
  for(int j=0;j<89;j++){
    float4 xv = *(const float4*)(xb + (size_t)j*1024 + c0);
    float fa=ca[j], fm=cm[j];
    aa0+=fa*xv.x; aa1+=fa*xv.y; aa2+=fa*xv.z; aa3+=fa*xv.w;
    am0+=fm*xv.x; am1+=fm*xv.y; am2+=fm*xv.z; am3+=fm*xv.w;
  }
  float4 xi = *(const float4*)(xb + (size_t)i*1024 + c0);
  size_t ro = ((size_t)(b*89 + i))*1024 + c0;
  ushort4 oa; oa.x=f2b(aa0); oa.y=f2b(aa1); oa.z=f2b(aa2); oa.w=f2b(aa3);
  ushort4 om;
  om.x=f2b(xi.x*am0); om.y=f2b(xi.y*am1);
  om.z=f2b(xi.z*am2); om.w=f2b(xi.w*am3);
  *(ushort4*)(a_t + ro) = oa;
  *(ushort4*)(m_t + ro) = om;
}

extern "C" void kernel_launch(void* const* d_in, const int* in_sizes, int n_in,
                              void* d_out, int out_size, void* d_ws, size_t ws_size,
                              hipStream_t stream)
{
  const float* X     = (const float*)d_in[0];
  const float* adjA  = (const float*)d_in[1];
  const float* adjM  = (const float*)d_in[2];
  const float* Wa1   = (const float*)d_in[3];
  const float* ba1   = (const float*)d_in[4];
  const float* Wa2   = (const float*)d_in[5];
  const float* ba2   = (const float*)d_in[6];
  const float* Wa3   = (const float*)d_in[7];
  const float* ba3   = (const float*)d_in[8];
  const float* Wadd1 = (const float*)d_in[9];
  const float* badd1 = (const float*)d_in[10];
  const float* Wadd2 = (const float*)d_in[11];
  const float* badd2 = (const float*)d_in[12];
  const float* Wmod1 = (const float*)d_in[13];
  const float* bmod1 = (const float*)d_in[14];
  const float* Wmod2 = (const float*)d_in[15];
  const float* bmod2 = (const float*)d_in[16];

  char* w = (char*)d_ws;
  u16* WaT1   = (u16*)w; w += (size_t)1024*1024*2;
  u16* WaT2   = (u16*)w; w += (size_t)512*1024*2;
  u16* WaddT1 = (u16*)w; w += (size_t)1024*1024*2;
  u16* WaddT2 = (u16*)w; w += (size_t)1024*1024*2;
  u16* WmodT1 = (u16*)w; w += (size_t)1024*1024*2;
  u16* WmodT2 = (u16*)w; w += (size_t)1024*1024*2;
  float* logit= (float*)w; w += (size_t)8*4096*4;
  u16* a_t    = (u16*)w; w += (size_t)768*1024*2;
  u16* m_t    = (u16*)w; w += (size_t)768*1024*2;
  u16* ha     = (u16*)w; w += (size_t)768*1024*2;
  u16* hm     = (u16*)w; w += (size_t)768*1024*2;   // must stay adjacent to ha
  size_t fixed = (size_t)(w - (char*)d_ws);
  size_t per_p = (size_t)4096*1024*2, per_h1 = (size_t)4096*1024*2;
  bool flat = ws_size >= fixed + 8*(per_p + per_h1);
  int nb = flat ? 8 : 1;
  u16* pbuf = (u16*)w; w += per_p  * nb;
  u16* h1   = (u16*)w;

  TrPack tp;
  tp.a[0].src = Wa1;   tp.a[0].dst = WaT1;   tp.a[0].C = 1024;
  tp.a[1].src = Wa2;   tp.a[1].dst = WaT2;   tp.a[1].C = 512;
  tp.a[2].src = Wadd1; tp.a[2].dst = WaddT1; tp.a[2].C = 1024;
  tp.a[3].src = Wadd2; tp.a[3].dst = WaddT2; tp.a[3].C = 1024;
  tp.a[4].src = Wmod1; tp.a[4].dst = WmodT1; tp.a[4].C = 1024;
  tp.a[5].src = Wmod2; tp.a[5].dst = WmodT2; tp.a[5].C = 1024;

  long pz = 4096*1024, h1z = 4096*1024;
  prep_k<<<dim3(6888 + 2048*nb), 256, 0, stream>>>(tp, logit, (float*)d_out, X, pbuf, pz);

  for(int bb=0; bb<8; bb+=nb){
    if(bb) pgen_k<<<dim3(4096,nb),256,0,stream>>>(X, pbuf, pz, bb);
    // layer1: M=4096 (32 mblk), N=1024 (8 nblk @ TN=128): y = n*32 + m
    gemm_k<0,0,128,128><<<dim3(1,256,nb),256,0,stream>>>(pbuf, WaT1, nullptr,nullptr, ba1,nullptr, nullptr,
                                                         h1, pz, h1z, 1024, 4096, 16, 31, 5, 4096);
    // layer2 + logit epilogue: M=4096 (32 mblk), N=512 (4 nblk @ TN=128)
    gemm_k<0,2,128,128><<<dim3(1,128,nb),256,0,stream>>>(h1, WaT2, nullptr,nullptr, ba2,nullptr, Wa3,
                                                         logit, h1z, 0, 0, bb, 16, 31, 5, 4096);
  }
  k4_k<<<dim3(89,8),256,0,stream>>>(X, adjA, adjM, logit, ba3, a_t, m_t);
  // tail hidden GEMMs (64x64 tiles): z=0 -> a_t@Wadd1 -> ha ; z=1 -> m_t@Wmod1 -> hm
  // M=768 -> 12 mblk (pad 16, mmask=15, mshift=4), N=1024 -> 16 nblk
  gemm_k<2,0,64,64><<<dim3(1,256,2),256,0,stream>>>(a_t, WaddT1, m_t, WmodT1, badd1, bmod1, nullptr,
                                                    ha, 0, (long)768*1024, 1024, 768, 16, 15, 4, 768);
  // final split-K (64x64): d_out zeroed in prep; z=0: ha@WaddT2 (+x+biases)/3, z=1: hm@WmodT2 /3
  gemm_k<2,3,64,64><<<dim3(1,256,2),256,0,stream>>>(ha, WaddT2, hm, WmodT2, badd2, bmod2, X,
                                                    d_out, 0, 0, 1024, 712, 16, 15, 4, 768);
}

// Round 8
// 271.087 us; speedup vs baseline: 1.5397x; 1.0048x over previous
//
#include <hip/hip_runtime.h>

typedef unsigned short u16;
typedef unsigned int   u32;
typedef __attribute__((ext_vector_type(8))) short bf16x8;
typedef __attribute__((ext_vector_type(4))) float f32x4;

#define DEVFN __device__ __forceinline__

DEVFN float b2f(u16 u){ u32 t=((u32)u)<<16; float f; __builtin_memcpy(&f,&t,4); return f; }
DEVFN u16 f2b(float f){ u32 t; __builtin_memcpy(&t,&f,4); t += 0x7fffu + ((t>>16)&1u); return (u16)(t>>16); }
DEVFN u32 pk2(float a, float b){ return (u32)f2b(a) | ((u32)f2b(b)<<16); }

// row -> (j,i) for upper-triangle pairs j<=i, N=89; base(j) = j*(179-j)/2
DEVFN void row2ji(int row, int* jj, int* ii){
  int j = (int)((179.0f - sqrtf(179.0f*179.0f - 8.0f*(float)row)) * 0.5f);
  if(j < 0) j = 0; if(j > 88) j = 88;
  while(j < 88 && (j+1)*(179-(j+1))/2 <= row) j++;
  while(j > 0 && j*(179-j)/2 > row) j--;
  *jj = j;
  *ii = j + (row - j*(179-j)/2);
}

struct TrArgs { const float* src; u16* dst; int C; };
struct TrPack { TrArgs a[6]; };

// ---------- fused prep:
// [0,6144)        weight transposes (32x32 tiles)
// [6144,6176)     logit zero (8*4096 fp32)
// [6176,6888)     d_out zero (712*1024 fp32)
// [6888,6888+2048*nb) pgen pairs: 2 rows per block, 16B stores
__global__ __launch_bounds__(256) void prep_k(TrPack pk, float* __restrict__ logit,
                                              float* __restrict__ dout,
                                              const float* __restrict__ x,
                                              u16* __restrict__ pbuf, long pz){
  __shared__ u16 tile[32][33];
  int id = blockIdx.x, tid = threadIdx.x;
  if(id < 6144){
    TrArgs t = pk.a[id>>10];
    int q = id & 1023;
    int bx = (q&31)*32, by = (q>>5)*32;
    if(bx >= t.C) return;
    int tx = tid&31, ty = tid>>5;
    #pragma unroll
    for(int yy=ty; yy<32; yy+=8) tile[yy][tx] = f2b(t.src[(size_t)(by+yy)*t.C + bx+tx]);
    __syncthreads();
    #pragma unroll
    for(int yy=ty; yy<32; yy+=8) t.dst[(size_t)(bx+yy)*1024 + by+tx] = tile[tx][yy];
  } else if(id < 6176){
    int idx = (id-6144)*1024 + tid*4;
    *(float4*)(logit + idx) = (float4){0.f,0.f,0.f,0.f};
  } else if(id < 6888){
    int idx = (id-6176)*1024 + tid*4;
    *(float4*)(dout + idx) = (float4){0.f,0.f,0.f,0.f};
  } else {
    int pid = id - 6888;
    int z = pid >> 11, rp = pid & 2047;
    int half = tid >> 7, t7 = tid & 127;
    int row = rp*2 + half;
    int j, i; row2ji(row < 4005 ? row : 0, &j, &i);
    const float* xb = x + (size_t)z*91136;
    int c = t7*8;
    float4 a0 = *(const float4*)(xb + (size_t)j*1024 + c);
    float4 a1 = *(const float4*)(xb + (size_t)j*1024 + c + 4);
    float4 b0 = *(const float4*)(xb + (size_t)i*1024 + c);
    float4 b1 = *(const float4*)(xb + (size_t)i*1024 + c + 4);
    uint4 o;
    o.x = pk2(a0.x*b0.x, a0.y*b0.y);
    o.y = pk2(a0.z*b0.z, a0.w*b0.w);
    o.z = pk2(a1.x*b1.x, a1.y*b1.y);
    o.w = pk2(a1.z*b1.z, a1.w*b1.w);
    *(uint4*)(pbuf + (size_t)z*pz + (size_t)row*1024 + c) = o;
  }
}

// standalone pgen for per-batch fallback iterations (1 row per block)
__global__ __launch_bounds__(256) void pgen_k(const float* __restrict__ x,
                                              u16* __restrict__ p, long pz, int bbase){
  int z = blockIdx.y, b = bbase + z, row = blockIdx.x;
  int j, i; row2ji(row < 4005 ? row : 0, &j, &i);
  const float* xb = x + (size_t)b*91136;
  int c = threadIdx.x*4;
  float4 a  = *(const float4*)(xb + (size_t)j*1024 + c);
  float4 bb = *(const float4*)(xb + (size_t)i*1024 + c);
  ushort4 o;
  o.x = f2b(a.x*bb.x); o.y = f2b(a.y*bb.y);
  o.z = f2b(a.z*bb.z); o.w = f2b(a.w*bb.w);
  *(ushort4*)(p + (size_t)z*pz + (size_t)row*1024 + c) = o;
}

// ---------- staging: ROWS x 64 k (bf16) via global_load_lds, XOR-swizzled k-blocks
template<int ROWS>
DEVFN void stage_gl(const u16* __restrict__ g0, u16* lds0, int tid){
  constexpr int IT = ROWS/32;
  int w = tid>>6, lane = tid&63;
  #pragma unroll
  for(int i=0;i<IT;i++){
    int p  = (w*IT+i)*64 + lane;
    int r  = p>>3;
    int kb = (p&7) ^ (r&7);
    const u16* g = g0 + ((size_t)r<<10) + (kb<<3);
    u16* l = lds0 + (size_t)(w*IT+i)*512;
    __builtin_amdgcn_global_load_lds((const __attribute__((address_space(1))) u32*)g,
                                     (__attribute__((address_space(3))) u32*)l, 16, 0, 0);
  }
}

// ---------- GEMM: tiles TMxTN, BK=64, 4 waves (2x2); blockIdx.y = n*mblkpad + m
// AMODE: 0 = single source (z = batch, A += z*a0z) ; 2 = z-select (z? A1,B1,bias1 : A0,B0,bias0)
// EPI:   0 = relu+bias -> bf16 out (+z*oz), LDS-staged coalesced write (requires TM*TN <= (TM+TN)*64)
//        2 = logit: relu+bias tile dot aux(=Wa3), lane-reduced, atomicAdd ((float*)out)[(aux2+z)*4096+row]
//        3 = split-K final: atomicAdd fp32 acc/3 into out; z==0 also adds (aux(x)+bias0+bias1)/3; row<aux2 guard
// MINW: min waves per EU for __launch_bounds__ (register/occupancy cap)
template<int AMODE, int EPI, int TM, int TN, int MINW>
__global__ __launch_bounds__(256,MINW) void gemm_k(
    const u16* __restrict__ A0, const u16* __restrict__ B0,
    const u16* __restrict__ A1, const u16* __restrict__ B1,
    const float* __restrict__ bias0, const float* __restrict__ bias1,
    const float* __restrict__ aux,
    void* __restrict__ out,
    long a0z, long oz, int ldo, int aux2, int kiters,
    int mmask, int mshift, int mlimit)
{
  constexpr int MB = TM/32, NB = TN/32;
  int by = blockIdx.y;
  int m0 = (by & mmask)*TM, n0 = (by >> mshift)*TN, z = blockIdx.z;
  if(m0 >= mlimit) return;   // block-uniform: safe before barriers

  __shared__ __align__(16) u16 smem[TM*64 + TN*64];
  u16* As = smem;
  u16* Bs = smem + TM*64;
  int tid = threadIdx.x;

  const u16* Abase0;
  const u16* Bbase0;
  if(AMODE==2){
    Abase0 = (z ? A1 : A0) + (size_t)m0*1024;
    Bbase0 = (z ? B1 : B0) + (size_t)n0*1024;
  } else {
    Abase0 = A0 + (size_t)z*a0z + (size_t)m0*1024;
    Bbase0 = B0 + (size_t)n0*1024;
  }

  f32x4 acc[MB][NB];
  #pragma unroll
  for(int a=0;a<MB;a++)
    #pragma unroll
    for(int b=0;b<NB;b++) acc[a][b] = (f32x4){0.f,0.f,0.f,0.f};

  int w = tid>>6, lane = tid&63, quad = lane>>4, l15 = lane&15;
  int wr = (w>>1)*(TM/2), wc = (w&1)*(TN/2);

  for(int kk=0; kk<kiters; kk++){
    int k0 = (kk & 15) << 6;
    const u16* Ab = Abase0 + k0;
    const u16* Bb = Bbase0 + k0;
    __syncthreads();
    stage_gl<TM>(Ab, As, tid);
    stage_gl<TN>(Bb, Bs, tid);
    __syncthreads();
    #pragma unroll
    for(int kq=0; kq<2; kq++){
      int kbl = kq*4 + quad;
      bf16x8 af[MB], bfv[NB];
      #pragma unroll
      for(int t=0;t<MB;t++){
        int rr = wr + t*16 + l15;
        af[t] = *(const bf16x8*)(As + rr*64 + ((kbl ^ (rr&7))<<3));
      }
      #pragma unroll
      for(int t=0;t<NB;t++){
        int cc = wc + t*16 + l15;
        bfv[t] = *(const bf16x8*)(Bs + cc*64 + ((kbl ^ (cc&7))<<3));
      }
      #pragma unroll
      for(int rt=0;rt<MB;rt++)
        #pragma unroll
        for(int ct=0;ct<NB;ct++)
          acc[rt][ct] = __builtin_amdgcn_mfma_f32_16x16x32_bf16(af[rt], bfv[ct], acc[rt][ct], 0,0,0);
    }
  }

  float bc[NB], w3[NB];
  #pragma unroll
  for(int ct=0;ct<NB;ct++){
    int colg = n0 + wc + ct*16 + l15;
    if(EPI==3){
      bc[ct] = (z==0) ? (bias0[colg] + bias1[colg]) : 0.f;
    } else {
      bc[ct] = (AMODE==2 && z) ? bias1[colg] : bias0[colg];
      if(EPI==2) w3[ct] = aux[colg];
    }
  }

  if(EPI==2){
    float part[MB][4];
    #pragma unroll
    for(int rt=0;rt<MB;rt++)
      #pragma unroll
      for(int r=0;r<4;r++) part[rt][r] = 0.f;
    #pragma unroll
    for(int rt=0;rt<MB;rt++)
      #pragma unroll
      for(int ct=0;ct<NB;ct++)
        #pragma unroll
        for(int r=0;r<4;r++)
          part[rt][r] += fmaxf(acc[rt][ct][r] + bc[ct], 0.f) * w3[ct];
    #pragma unroll
    for(int m=1;m<16;m<<=1)
      #pragma unroll
      for(int rt=0;rt<MB;rt++)
        #pragma unroll
        for(int r=0;r<4;r++)
          part[rt][r] += __shfl_xor(part[rt][r], m, 64);
    if(l15==0){
      float* lo = (float*)out + (size_t)(aux2 + z)*4096;
      #pragma unroll
      for(int rt=0;rt<MB;rt++)
        #pragma unroll
        for(int r=0;r<4;r++)
          atomicAdd(lo + (m0 + wr + rt*16 + quad*4 + r), part[rt][r]);
    }
    return;
  }

  if(EPI==3){
    const float third = 1.f/3.f;
    float* op = (float*)out;
    #pragma unroll
    for(int ct=0;ct<NB;ct++){
      int colg = n0 + wc + ct*16 + l15;
      #pragma unroll
      for(int rt=0;rt<MB;rt++){
        #pragma unroll
        for(int r=0;r<4;r++){
          int rowg = m0 + wr + rt*16 + quad*4 + r;
          if(rowg < aux2){
            float v = acc[rt][ct][r];
            if(z==0) v += aux[(size_t)rowg*1024 + colg] + bc[ct];
            atomicAdd(op + (size_t)rowg*ldo + colg, v*third);
          }
        }
      }
    }
    return;
  }

  // EPI==0: stage C tile (TM x TN bf16) in LDS, then coalesced 16B stores
  __syncthreads();
  u16* Ct = smem;
  #pragma unroll
  for(int ct=0;ct<NB;ct++){
    int cl = wc + ct*16 + l15;
    #pragma unroll
    for(int rt=0;rt<MB;rt++){
      #pragma unroll
      for(int r=0;r<4;r++){
        int rl = wr + rt*16 + quad*4 + r;
        Ct[rl*TN + cl] = f2b(fmaxf(acc[rt][ct][r] + bc[ct], 0.f));
      }
    }
  }
  __syncthreads();
  u16* outp = (u16*)out + (size_t)z*oz;
  #pragma unroll
  for(int i=0;i<TM*TN/2048;i++){
    int q = i*256 + tid;
    int row = q/(TN/8), c16 = q%(TN/8);
    *(uint4*)(outp + (size_t)(m0+row)*ldo + n0 + c16*8) = *(const uint4*)(Ct + row*TN + c16*8);
  }
}

// ---------- AddConv / ModulatorConv aggregation -> a_t, m_t (bf16); sigmoid applied here
__global__ __launch_bounds__(256) void k4_k(const float* __restrict__ x,
    const float* __restrict__ adjA, const float* __restrict__ adjM,
    const float* __restrict__ logit, const float* __restrict__ ba3,
    u16* __restrict__ a_t, u16* __restrict__ m_t)
{
  int b = blockIdx.y, i = blockIdx.x, t = threadIdx.x;
  __shared__ float ca[89], cm[89];
  if(t < 89){
    int tri = (t<=i) ? t*(179-t)/2 + (i-t) : i*(179-i)/2 + (t-i);
    float lg = logit[(size_t)b*4096 + tri] + ba3[0];
    float sv = 1.f/(1.f + expf(-lg));
    ca[t] = sv * adjA[t*89 + i];
    cm[t] = adjM[t*89 + i];
  }
  __syncthreads();
  const float* xb = x + (size_t)b*91136;
  int c0 = t*4;
  float aa0=0,aa1=0,aa2=0,aa3=0, am0=0,am1=0,am2=0,am3=0;
  #pragma unroll 8
  for(int j=0;j<89;j++){
    float4 xv = *(const float4*)(xb + (size_t)j*1024 + c0);
    float fa=ca[j], fm=cm[j];
    aa0+=fa*xv.x; aa1+=fa*xv.y; aa2+=fa*xv.z; aa3+=fa*xv.w;
    am0+=fm*xv.x; am1+=fm*xv.y; am2+=fm*xv.z; am3+=fm*xv.w;
  }
  float4 xi = *(const float4*)(xb + (size_t)i*1024 + c0);
  size_t ro = ((size_t)(b*89 + i))*1024 + c0;
  ushort4 oa; oa.x=f2b(aa0); oa.y=f2b(aa1); oa.z=f2b(aa2); oa.w=f2b(aa3);
  ushort4 om;
  om.x=f2b(xi.x*am0); om.y=f2b(xi.y*am1);
  om.z=f2b(xi.z*am2); om.w=f2b(xi.w*am3);
  *(ushort4*)(a_t + ro) = oa;
  *(ushort4*)(m_t + ro) = om;
}

extern "C" void kernel_launch(void* const* d_in, const int* in_sizes, int n_in,
                              void* d_out, int out_size, void* d_ws, size_t ws_size,
                              hipStream_t stream)
{
  const float* X     = (const float*)d_in[0];
  const float* adjA  = (const float*)d_in[1];
  const float* adjM  = (const float*)d_in[2];
  const float* Wa1   = (const float*)d_in[3];
  const float* ba1   = (const float*)d_in[4];
  const float* Wa2   = (const float*)d_in[5];
  const float* ba2   = (const float*)d_in[6];
  const float* Wa3   = (const float*)d_in[7];
  const float* ba3   = (const float*)d_in[8];
  const float* Wadd1 = (const float*)d_in[9];
  const float* badd1 = (const float*)d_in[10];
  const float* Wadd2 = (const float*)d_in[11];
  const float* badd2 = (const float*)d_in[12];
  const float* Wmod1 = (const float*)d_in[13];
  const float* bmod1 = (const float*)d_in[14];
  const float* Wmod2 = (const float*)d_in[15];
  const float* bmod2 = (const float*)d_in[16];

  char* w = (char*)d_ws;
  u16* WaT1   = (u16*)w; w += (size_t)1024*1024*2;
  u16* WaT2   = (u16*)w; w += (size_t)512*1024*2;
  u16* WaddT1 = (u16*)w; w += (size_t)1024*1024*2;
  u16* WaddT2 = (u16*)w; w += (size_t)1024*1024*2;
  u16* WmodT1 = (u16*)w; w += (size_t)1024*1024*2;
  u16* WmodT2 = (u16*)w; w += (size_t)1024*1024*2;
  float* logit= (float*)w; w += (size_t)8*4096*4;
  u16* a_t    = (u16*)w; w += (size_t)768*1024*2;
  u16* m_t    = (u16*)w; w += (size_t)768*1024*2;
  u16* ha     = (u16*)w; w += (size_t)768*1024*2;
  u16* hm     = (u16*)w; w += (size_t)768*1024*2;   // must stay adjacent to ha
  size_t fixed = (size_t)(w - (char*)d_ws);
  size_t per_p = (size_t)4096*1024*2, per_h1 = (size_t)4096*1024*2;
  bool flat = ws_size >= fixed + 8*(per_p + per_h1);
  int nb = flat ? 8 : 1;
  u16* pbuf = (u16*)w; w += per_p  * nb;
  u16* h1   = (u16*)w;

  TrPack tp;
  tp.a[0].src = Wa1;   tp.a[0].dst = WaT1;   tp.a[0].C = 1024;
  tp.a[1].src = Wa2;   tp.a[1].dst = WaT2;   tp.a[1].C = 512;
  tp.a[2].src = Wadd1; tp.a[2].dst = WaddT1; tp.a[2].C = 1024;
  tp.a[3].src = Wadd2; tp.a[3].dst = WaddT2; tp.a[3].C = 1024;
  tp.a[4].src = Wmod1; tp.a[4].dst = WmodT1; tp.a[4].C = 1024;
  tp.a[5].src = Wmod2; tp.a[5].dst = WmodT2; tp.a[5].C = 1024;

  long pz = 4096*1024, h1z = 4096*1024;
  prep_k<<<dim3(6888 + 2048*nb), 256, 0, stream>>>(tp, logit, (float*)d_out, X, pbuf, pz);

  for(int bb=0; bb<8; bb+=nb){
    if(bb) pgen_k<<<dim3(4096,nb),256,0,stream>>>(X, pbuf, pz, bb);
    // layer1: M=4096 (32 mblk), N=1024 (8 nblk @ TN=128): y = n*32 + m; 3 blocks/CU
    gemm_k<0,0,128,128,3><<<dim3(1,256,nb),256,0,stream>>>(pbuf, WaT1, nullptr,nullptr, ba1,nullptr, nullptr,
                                                           h1, pz, h1z, 1024, 4096, 16, 31, 5, 4096);
    // layer2 + logit epilogue: M=4096 (32 mblk), N=512 (2 nblk @ TN=256)
    gemm_k<0,2,128,256,2><<<dim3(1,64,nb),256,0,stream>>>(h1, WaT2, nullptr,nullptr, ba2,nullptr, Wa3,
                                                          logit, h1z, 0, 0, bb, 16, 31, 5, 4096);
  }
  k4_k<<<dim3(89,8),256,0,stream>>>(X, adjA, adjM, logit, ba3, a_t, m_t);
  // tail hidden GEMMs (64x64 tiles, 4 blocks/CU): z=0 -> a_t@Wadd1 -> ha ; z=1 -> m_t@Wmod1 -> hm
  gemm_k<2,0,64,64,4><<<dim3(1,256,2),256,0,stream>>>(a_t, WaddT1, m_t, WmodT1, badd1, bmod1, nullptr,
                                                      ha, 0, (long)768*1024, 1024, 768, 16, 15, 4, 768);
  // final split-K (64x64): d_out zeroed in prep; z=0: ha@WaddT2 (+x+biases)/3, z=1: hm@WmodT2 /3
  gemm_k<2,3,64,64,4><<<dim3(1,256,2),256,0,stream>>>(ha, WaddT2, hm, WmodT2, badd2, bmod2, X,
                                                      d_out, 0, 0, 1024, 712, 16, 15, 4, 768);
}